// Round 9
// baseline (673.896 us; speedup 1.0000x reference)
//
#include <hip/hip_runtime.h>
#include <hip/hip_cooperative_groups.h>

namespace cg = cooperative_groups;

#define EPS_BN 1e-5f
#define NEG_SLOPE 0.01f

#define BINSHIFT 9
#define BINSIZE (1 << BINSHIFT)
#define NBINS_LDS 200
#define BUFCAP 24
#define GSTRIDE 16
#define NBLK 768                   // coop grid: 3/CU needed, 4/CU capacity (25.4KB LDS, VGPR<=128)
#define NTHR 256

__device__ __forceinline__ uint32_t pack2_bf16(float x, float y) {
    uint32_t ux = __float_as_uint(x);
    uint32_t uy = __float_as_uint(y);
    ux = (ux + 0x7fffu + ((ux >> 16) & 1u)) >> 16;
    uy = (uy + 0x7fffu + ((uy >> 16) & 1u)) >> 16;
    return (uy << 16) | (ux & 0xffffu);
}
__device__ __forceinline__ float bf_lo(uint32_t p) { return __uint_as_float(p << 16); }
__device__ __forceinline__ float bf_hi(uint32_t p) { return __uint_as_float(p & 0xffff0000u); }

// ===================== standalone kernels (fallback path, R8-proven) =====================
__global__ void __launch_bounds__(256) stage_ms_kernel(
        const int* __restrict__ src, const int* __restrict__ dst,
        int* __restrict__ gcur, uint32_t* __restrict__ staged,
        int cap, int nbins, int E, int chunk) {
    __shared__ uint32_t bbuf[NBINS_LDS][BUFCAP];
    __shared__ int bcnt[NBINS_LDS];
    __shared__ int gpos[NBINS_LDS];
    for (int i = threadIdx.x; i < nbins; i += 256) bcnt[i] = 0;
    __syncthreads();
    int e0 = blockIdx.x * chunk;
    int e1 = min(e0 + chunk, E);
    for (int base = e0; base < e1; base += 1024) {
        int e = base + threadIdx.x * 4;
        int s0, s1, s2, s3, d0, d1, d2, d3;
        int ne = 0;
        if (e + 4 <= e1) {
            int4 s4 = *(const int4*)(src + e);
            int4 d4 = *(const int4*)(dst + e);
            s0 = s4.x; s1 = s4.y; s2 = s4.z; s3 = s4.w;
            d0 = d4.x; d1 = d4.y; d2 = d4.z; d3 = d4.w;
            ne = 4;
        } else {
            int k = 0;
            for (; e + k < e1 && k < 4; ++k) {
                int sv = src[e + k], dv = dst[e + k];
                if (k == 0) { s0 = sv; d0 = dv; }
                else if (k == 1) { s1 = sv; d1 = dv; }
                else if (k == 2) { s2 = sv; d2 = dv; }
                else { s3 = sv; d3 = dv; }
            }
            ne = k;
        }
        #pragma unroll
        for (int k = 0; k < 4; ++k) {
            if (k >= ne) break;
            int s = (k == 0) ? s0 : (k == 1) ? s1 : (k == 2) ? s2 : s3;
            int d = (k == 0) ? d0 : (k == 1) ? d1 : (k == 2) ? d2 : d3;
            int bin = d >> BINSHIFT;
            uint32_t rec = ((uint32_t)s << BINSHIFT) | (uint32_t)(d & (BINSIZE - 1));
            int pos = atomicAdd(&bcnt[bin], 1);
            if (pos < BUFCAP) bbuf[bin][pos] = rec;
            else {
                int gp = atomicAdd(&gcur[bin * GSTRIDE], 1);
                staged[(size_t)bin * cap + gp] = rec;
            }
        }
    }
    __syncthreads();
    for (int b = threadIdx.x; b < nbins; b += 256) {
        int c = min(bcnt[b], BUFCAP);
        gpos[b] = (c > 0) ? atomicAdd(&gcur[b * GSTRIDE], c) : 0;
    }
    __syncthreads();
    int grp = threadIdx.x >> 4, lane = threadIdx.x & 15;
    for (int b = grp; b < nbins; b += 16) {
        int c = min(bcnt[b], BUFCAP);
        int gp = gpos[b];
        for (int i = lane; i < c; i += 16)
            staged[(size_t)b * cap + gp + i] = bbuf[b][i];
    }
}

__global__ void __launch_bounds__(256) fill_csr_kernel(
        const uint32_t* __restrict__ staged, const int* __restrict__ gcur,
        const float* __restrict__ x, int cap, int nbins,
        int* __restrict__ rowptr, int* __restrict__ cnt,
        float* __restrict__ dinv, float4* __restrict__ xs,
        int* __restrict__ eidx, int N,
        float* __restrict__ out, float* __restrict__ gcnt, int G) {
    __shared__ int lcnt[BINSIZE];
    __shared__ int loff[BINSIZE];
    __shared__ int ps[256];
    int bin = blockIdx.x;
    int v = (threadIdx.x < nbins && threadIdx.x < bin) ? gcur[threadIdx.x * GSTRIDE] : 0;
    ps[threadIdx.x] = v;
    __syncthreads();
    for (int off = 128; off; off >>= 1) {
        if (threadIdx.x < off) ps[threadIdx.x] += ps[threadIdx.x + off];
        __syncthreads();
    }
    int bb = ps[0];
    __syncthreads();
    if (bin == 0) {
        for (int i = threadIdx.x; i < G * 32; i += 256) out[i] = 0.f;
        for (int i = threadIdx.x; i < G; i += 256) gcnt[i] = 0.f;
    }
    int node0 = bin << BINSHIFT;
    int nn = min(BINSIZE, N - node0);
    int nrec = gcur[bin * GSTRIDE];
    const uint32_t* recs = staged + (size_t)bin * cap;
    for (int i = threadIdx.x; i < BINSIZE; i += 256) lcnt[i] = 0;
    __syncthreads();
    for (int t = threadIdx.x; t < nrec; t += 256)
        atomicAdd(&lcnt[recs[t] & (BINSIZE - 1)], 1);
    __syncthreads();
    int p0 = lcnt[2 * threadIdx.x], p1 = lcnt[2 * threadIdx.x + 1];
    int pv = p0 + p1;
    ps[threadIdx.x] = pv;
    __syncthreads();
    for (int off = 1; off < 256; off <<= 1) {
        int t = (threadIdx.x >= off) ? ps[threadIdx.x - off] : 0;
        __syncthreads();
        ps[threadIdx.x] += t;
        __syncthreads();
    }
    int base = ps[threadIdx.x] - pv;
    loff[2 * threadIdx.x] = base;
    loff[2 * threadIdx.x + 1] = base + p0;
    __syncthreads();
    for (int i = threadIdx.x; i < nn; i += 256) {
        int node = node0 + i;
        rowptr[node] = bb + loff[i];
        cnt[node] = lcnt[i];
        float di = rsqrtf((float)(lcnt[i] + 1));
        dinv[node] = di;
        const float* xr = x + (size_t)node * 3;
        xs[node] = make_float4(xr[0] * di, xr[1] * di, xr[2] * di, 0.f);
        lcnt[i] = 0;
    }
    __syncthreads();
    for (int t = threadIdx.x; t < nrec; t += 256) {
        uint32_t r = recs[t];
        int li = r & (BINSIZE - 1);
        int p = atomicAdd(&lcnt[li], 1);
        eidx[bb + loff[li] + p] = (int)(r >> BINSHIFT);
    }
}

// ---- phase bodies shared by fallback kernels and mega kernel ----
struct SL1 { float sW1[192]; float sSc[64]; float sSh[64]; float sW2[4096]; float sH[32][64]; float sDinv[32]; };
struct SL2 { float sW3[2048]; float sSc[64]; float sSh[64]; float sH[32][64]; float sDinv[32]; };
struct SL3 { float sSc[32]; float sSh[32]; float sAcc[16][32]; int sCnt[16]; };

__device__ __forceinline__ void layer1_body(SL1& S, int vb,
        const float4* __restrict__ xs, const int* __restrict__ rowptr,
        const int* __restrict__ cnt, const int* __restrict__ eidx,
        const float* __restrict__ dinv, uint32_t* Tp, int N) {
    int tid = threadIdx.x;
    int lane = tid & 7;
    int nl = tid >> 3;
    int node = vb * 32 + nl;
    int m = min(node, N - 1);
    int start = rowptr[m], deg = cnt[m];
    float ax = 0.f, ay = 0.f, az = 0.f;
    for (int j = lane; j < deg; j += 8) {
        float4 v = xs[eidx[start + j]];
        ax += v.x; ay += v.y; az += v.z;
    }
    #pragma unroll
    for (int o = 4; o; o >>= 1) {
        ax += __shfl_xor(ax, o, 8);
        ay += __shfl_xor(ay, o, 8);
        az += __shfl_xor(az, o, 8);
    }
    float4 self = xs[m];
    float di = dinv[m];
    float gx = (ax + self.x) * di, gy = (ay + self.y) * di, gz = (az + self.z) * di;
    if (lane == 0) S.sDinv[nl] = di;
    int f0 = lane * 8;
    #pragma unroll
    for (int hh = 0; hh < 2; ++hh) {
        float4 hv;
        #pragma unroll
        for (int q = 0; q < 4; ++q) {
            int f = f0 + 4 * hh + q;
            float a = gx * S.sW1[f] + gy * S.sW1[64 + f] + gz * S.sW1[128 + f];
            float y = a * S.sSc[f] + S.sSh[f];
            ((float*)&hv)[q] = (y >= 0.f) ? y : NEG_SLOPE * y;
        }
        *(float4*)&S.sH[nl][f0 + 4 * hh] = hv;
    }
    __syncthreads();
    int fp = tid & 31;
    int ng = tid >> 5;
    const float2* w2 = (const float2*)S.sW2 + fp;
    const float4* sH0 = (const float4*)&S.sH[ng][0];
    const float4* sH1 = (const float4*)&S.sH[ng + 8][0];
    const float4* sH2 = (const float4*)&S.sH[ng + 16][0];
    const float4* sH3 = (const float4*)&S.sH[ng + 24][0];
    float a00 = 0.f, a01 = 0.f, a10 = 0.f, a11 = 0.f;
    float a20 = 0.f, a21 = 0.f, a30 = 0.f, a31 = 0.f;
    #pragma unroll 4
    for (int k4 = 0; k4 < 16; ++k4) {
        float4 h0 = sH0[k4];
        float4 h1 = sH1[k4];
        float4 h2 = sH2[k4];
        float4 h3 = sH3[k4];
        float2 w;
        w = w2[(4 * k4 + 0) * 32];
        a00 = fmaf(h0.x, w.x, a00); a01 = fmaf(h0.x, w.y, a01);
        a10 = fmaf(h1.x, w.x, a10); a11 = fmaf(h1.x, w.y, a11);
        a20 = fmaf(h2.x, w.x, a20); a21 = fmaf(h2.x, w.y, a21);
        a30 = fmaf(h3.x, w.x, a30); a31 = fmaf(h3.x, w.y, a31);
        w = w2[(4 * k4 + 1) * 32];
        a00 = fmaf(h0.y, w.x, a00); a01 = fmaf(h0.y, w.y, a01);
        a10 = fmaf(h1.y, w.x, a10); a11 = fmaf(h1.y, w.y, a11);
        a20 = fmaf(h2.y, w.x, a20); a21 = fmaf(h2.y, w.y, a21);
        a30 = fmaf(h3.y, w.x, a30); a31 = fmaf(h3.y, w.y, a31);
        w = w2[(4 * k4 + 2) * 32];
        a00 = fmaf(h0.z, w.x, a00); a01 = fmaf(h0.z, w.y, a01);
        a10 = fmaf(h1.z, w.x, a10); a11 = fmaf(h1.z, w.y, a11);
        a20 = fmaf(h2.z, w.x, a20); a21 = fmaf(h2.z, w.y, a21);
        a30 = fmaf(h3.z, w.x, a30); a31 = fmaf(h3.z, w.y, a31);
        w = w2[(4 * k4 + 3) * 32];
        a00 = fmaf(h0.w, w.x, a00); a01 = fmaf(h0.w, w.y, a01);
        a10 = fmaf(h1.w, w.x, a10); a11 = fmaf(h1.w, w.y, a11);
        a20 = fmaf(h2.w, w.x, a20); a21 = fmaf(h2.w, w.y, a21);
        a30 = fmaf(h3.w, w.x, a30); a31 = fmaf(h3.w, w.y, a31);
    }
    int base = vb * 32;
    int n0 = base + ng, n1 = base + ng + 8, n2 = base + ng + 16, n3 = base + ng + 24;
    if (n0 < N) { float d = S.sDinv[ng];      Tp[(size_t)n0 * 32 + fp] = pack2_bf16(a00 * d, a01 * d); }
    if (n1 < N) { float d = S.sDinv[ng + 8];  Tp[(size_t)n1 * 32 + fp] = pack2_bf16(a10 * d, a11 * d); }
    if (n2 < N) { float d = S.sDinv[ng + 16]; Tp[(size_t)n2 * 32 + fp] = pack2_bf16(a20 * d, a21 * d); }
    if (n3 < N) { float d = S.sDinv[ng + 24]; Tp[(size_t)n3 * 32 + fp] = pack2_bf16(a30 * d, a31 * d); }
}

__device__ __forceinline__ void layer2_body(SL2& S, int vb,
        const uint32_t* Tp, const int* __restrict__ rowptr,
        const int* __restrict__ cnt, const int* __restrict__ eidx,
        const float* __restrict__ dinv, uint32_t* Tp2, int N) {
    int tid = threadIdx.x;
    int fq = tid & 7;
    int nl = tid >> 3;
    int node = vb * 32 + nl;
    int m = min(node, N - 1);
    const uint4* T4 = (const uint4*)Tp + fq;
    int start = rowptr[m];
    int deg = cnt[m];
    uint4 ts = T4[(size_t)m * 8];
    float a0 = bf_lo(ts.x), a1 = bf_hi(ts.x), a2 = bf_lo(ts.y), a3 = bf_hi(ts.y);
    float a4 = bf_lo(ts.z), a5 = bf_hi(ts.z), a6 = bf_lo(ts.w), a7 = bf_hi(ts.w);
    float c0 = 0.f, c1 = 0.f, c2 = 0.f, c3 = 0.f;
    float c4 = 0.f, c5 = 0.f, c6 = 0.f, c7 = 0.f;
    const int* ep = eidx + start;
    int j = 0;
    int s0, s1, s2, s3;
    if (deg >= 4) { s0 = ep[0]; s1 = ep[1]; s2 = ep[2]; s3 = ep[3]; }
    for (; j + 8 <= deg; j += 4) {
        uint4 t0 = T4[(size_t)s0 * 8];
        uint4 t1 = T4[(size_t)s1 * 8];
        uint4 t2 = T4[(size_t)s2 * 8];
        uint4 t3 = T4[(size_t)s3 * 8];
        s0 = ep[j + 4]; s1 = ep[j + 5]; s2 = ep[j + 6]; s3 = ep[j + 7];
        a0 += bf_lo(t0.x) + bf_lo(t2.x);  a1 += bf_hi(t0.x) + bf_hi(t2.x);
        a2 += bf_lo(t0.y) + bf_lo(t2.y);  a3 += bf_hi(t0.y) + bf_hi(t2.y);
        a4 += bf_lo(t0.z) + bf_lo(t2.z);  a5 += bf_hi(t0.z) + bf_hi(t2.z);
        a6 += bf_lo(t0.w) + bf_lo(t2.w);  a7 += bf_hi(t0.w) + bf_hi(t2.w);
        c0 += bf_lo(t1.x) + bf_lo(t3.x);  c1 += bf_hi(t1.x) + bf_hi(t3.x);
        c2 += bf_lo(t1.y) + bf_lo(t3.y);  c3 += bf_hi(t1.y) + bf_hi(t3.y);
        c4 += bf_lo(t1.z) + bf_lo(t3.z);  c5 += bf_hi(t1.z) + bf_hi(t3.z);
        c6 += bf_lo(t1.w) + bf_lo(t3.w);  c7 += bf_hi(t1.w) + bf_hi(t3.w);
    }
    if (j + 4 <= deg) {
        uint4 t0 = T4[(size_t)s0 * 8];
        uint4 t1 = T4[(size_t)s1 * 8];
        uint4 t2 = T4[(size_t)s2 * 8];
        uint4 t3 = T4[(size_t)s3 * 8];
        a0 += bf_lo(t0.x) + bf_lo(t2.x);  a1 += bf_hi(t0.x) + bf_hi(t2.x);
        a2 += bf_lo(t0.y) + bf_lo(t2.y);  a3 += bf_hi(t0.y) + bf_hi(t2.y);
        a4 += bf_lo(t0.z) + bf_lo(t2.z);  a5 += bf_hi(t0.z) + bf_hi(t2.z);
        a6 += bf_lo(t0.w) + bf_lo(t2.w);  a7 += bf_hi(t0.w) + bf_hi(t2.w);
        c0 += bf_lo(t1.x) + bf_lo(t3.x);  c1 += bf_hi(t1.x) + bf_hi(t3.x);
        c2 += bf_lo(t1.y) + bf_lo(t3.y);  c3 += bf_hi(t1.y) + bf_hi(t3.y);
        c4 += bf_lo(t1.z) + bf_lo(t3.z);  c5 += bf_hi(t1.z) + bf_hi(t3.z);
        c6 += bf_lo(t1.w) + bf_lo(t3.w);  c7 += bf_hi(t1.w) + bf_hi(t3.w);
        j += 4;
    }
    for (; j < deg; ++j) {
        uint4 t0 = T4[(size_t)ep[j] * 8];
        a0 += bf_lo(t0.x); a1 += bf_hi(t0.x);
        a2 += bf_lo(t0.y); a3 += bf_hi(t0.y);
        a4 += bf_lo(t0.z); a5 += bf_hi(t0.z);
        a6 += bf_lo(t0.w); a7 += bf_hi(t0.w);
    }
    float di = dinv[m];
    if (fq == 0) S.sDinv[nl] = di;
    int f0 = 8 * fq;
    float av[8] = {a0 + c0, a1 + c1, a2 + c2, a3 + c3,
                   a4 + c4, a5 + c5, a6 + c6, a7 + c7};
    #pragma unroll
    for (int hh = 0; hh < 2; ++hh) {
        float4 hv;
        #pragma unroll
        for (int q = 0; q < 4; ++q) {
            int f = f0 + 4 * hh + q;
            float y = av[4 * hh + q] * di * S.sSc[f] + S.sSh[f];
            ((float*)&hv)[q] = (y >= 0.f) ? y : NEG_SLOPE * y;
        }
        *(float4*)&S.sH[nl][f0 + 4 * hh] = hv;
    }
    __syncthreads();
    int fp = tid & 15;
    int ng = tid >> 4;
    const float2* w3 = (const float2*)S.sW3 + fp;
    const float4* sHA = (const float4*)&S.sH[ng][0];
    const float4* sHB = (const float4*)&S.sH[ng + 16][0];
    float p0 = 0.f, p1 = 0.f, q0 = 0.f, q1 = 0.f;
    #pragma unroll 4
    for (int k4 = 0; k4 < 16; ++k4) {
        float4 hA = sHA[k4];
        float4 hB = sHB[k4];
        float2 w;
        w = w3[(4 * k4 + 0) * 16];
        p0 = fmaf(hA.x, w.x, p0); p1 = fmaf(hA.x, w.y, p1);
        q0 = fmaf(hB.x, w.x, q0); q1 = fmaf(hB.x, w.y, q1);
        w = w3[(4 * k4 + 1) * 16];
        p0 = fmaf(hA.y, w.x, p0); p1 = fmaf(hA.y, w.y, p1);
        q0 = fmaf(hB.y, w.x, q0); q1 = fmaf(hB.y, w.y, q1);
        w = w3[(4 * k4 + 2) * 16];
        p0 = fmaf(hA.z, w.x, p0); p1 = fmaf(hA.z, w.y, p1);
        q0 = fmaf(hB.z, w.x, q0); q1 = fmaf(hB.z, w.y, q1);
        w = w3[(4 * k4 + 3) * 16];
        p0 = fmaf(hA.w, w.x, p0); p1 = fmaf(hA.w, w.y, p1);
        q0 = fmaf(hB.w, w.x, q0); q1 = fmaf(hB.w, w.y, q1);
    }
    int base = vb * 32;
    int nA = base + ng, nB = base + ng + 16;
    if (nA < N) { float d = S.sDinv[ng];      Tp2[(size_t)nA * 16 + fp] = pack2_bf16(p0 * d, p1 * d); }
    if (nB < N) { float d = S.sDinv[ng + 16]; Tp2[(size_t)nB * 16 + fp] = pack2_bf16(q0 * d, q1 * d); }
}

__device__ __forceinline__ void layer3_body(SL3& S, int vb,
        const uint32_t* Tp2, const int* __restrict__ rowptr,
        const int* __restrict__ cnt, const int* __restrict__ eidx,
        const float* __restrict__ dinv, const int* __restrict__ batch,
        float* __restrict__ out, float* __restrict__ gcnt, int N) {
    int tid = threadIdx.x;
    for (int i = tid; i < 16 * 32; i += 256) ((float*)S.sAcc)[i] = 0.f;
    if (tid < 16) S.sCnt[tid] = 0;
    __syncthreads();
    int fq = tid & 3;
    int nl = tid >> 2;
    int node = vb * 64 + nl;
    bool valid = node < N;
    int m = valid ? node : N - 1;
    const uint4* T4 = (const uint4*)Tp2 + fq;
    int start = rowptr[m];
    int deg = cnt[m];
    uint4 ts = T4[(size_t)m * 4];
    float a0 = bf_lo(ts.x), a1 = bf_hi(ts.x), a2 = bf_lo(ts.y), a3 = bf_hi(ts.y);
    float a4 = bf_lo(ts.z), a5 = bf_hi(ts.z), a6 = bf_lo(ts.w), a7 = bf_hi(ts.w);
    float c0 = 0.f, c1 = 0.f, c2 = 0.f, c3 = 0.f;
    float c4 = 0.f, c5 = 0.f, c6 = 0.f, c7 = 0.f;
    const int* ep = eidx + start;
    int j = 0;
    int s0, s1, s2, s3;
    if (deg >= 4) { s0 = ep[0]; s1 = ep[1]; s2 = ep[2]; s3 = ep[3]; }
    for (; j + 8 <= deg; j += 4) {
        uint4 t0 = T4[(size_t)s0 * 4];
        uint4 t1 = T4[(size_t)s1 * 4];
        uint4 t2 = T4[(size_t)s2 * 4];
        uint4 t3 = T4[(size_t)s3 * 4];
        s0 = ep[j + 4]; s1 = ep[j + 5]; s2 = ep[j + 6]; s3 = ep[j + 7];
        a0 += bf_lo(t0.x) + bf_lo(t2.x);  a1 += bf_hi(t0.x) + bf_hi(t2.x);
        a2 += bf_lo(t0.y) + bf_lo(t2.y);  a3 += bf_hi(t0.y) + bf_hi(t2.y);
        a4 += bf_lo(t0.z) + bf_lo(t2.z);  a5 += bf_hi(t0.z) + bf_hi(t2.z);
        a6 += bf_lo(t0.w) + bf_lo(t2.w);  a7 += bf_hi(t0.w) + bf_hi(t2.w);
        c0 += bf_lo(t1.x) + bf_lo(t3.x);  c1 += bf_hi(t1.x) + bf_hi(t3.x);
        c2 += bf_lo(t1.y) + bf_lo(t3.y);  c3 += bf_hi(t1.y) + bf_hi(t3.y);
        c4 += bf_lo(t1.z) + bf_lo(t3.z);  c5 += bf_hi(t1.z) + bf_hi(t3.z);
        c6 += bf_lo(t1.w) + bf_lo(t3.w);  c7 += bf_hi(t1.w) + bf_hi(t3.w);
    }
    if (j + 4 <= deg) {
        uint4 t0 = T4[(size_t)s0 * 4];
        uint4 t1 = T4[(size_t)s1 * 4];
        uint4 t2 = T4[(size_t)s2 * 4];
        uint4 t3 = T4[(size_t)s3 * 4];
        a0 += bf_lo(t0.x) + bf_lo(t2.x);  a1 += bf_hi(t0.x) + bf_hi(t2.x);
        a2 += bf_lo(t0.y) + bf_lo(t2.y);  a3 += bf_hi(t0.y) + bf_hi(t2.y);
        a4 += bf_lo(t0.z) + bf_lo(t2.z);  a5 += bf_hi(t0.z) + bf_hi(t2.z);
        a6 += bf_lo(t0.w) + bf_lo(t2.w);  a7 += bf_hi(t0.w) + bf_hi(t2.w);
        c0 += bf_lo(t1.x) + bf_lo(t3.x);  c1 += bf_hi(t1.x) + bf_hi(t3.x);
        c2 += bf_lo(t1.y) + bf_lo(t3.y);  c3 += bf_hi(t1.y) + bf_hi(t3.y);
        c4 += bf_lo(t1.z) + bf_lo(t3.z);  c5 += bf_hi(t1.z) + bf_hi(t3.z);
        c6 += bf_lo(t1.w) + bf_lo(t3.w);  c7 += bf_hi(t1.w) + bf_hi(t3.w);
        j += 4;
    }
    for (; j < deg; ++j) {
        uint4 t0 = T4[(size_t)ep[j] * 4];
        a0 += bf_lo(t0.x); a1 += bf_hi(t0.x);
        a2 += bf_lo(t0.y); a3 += bf_hi(t0.y);
        a4 += bf_lo(t0.z); a5 += bf_hi(t0.z);
        a6 += bf_lo(t0.w); a7 += bf_hi(t0.w);
    }
    float di = dinv[m];
    int f0 = 8 * fq;
    float av[8] = {a0 + c0, a1 + c1, a2 + c2, a3 + c3,
                   a4 + c4, a5 + c5, a6 + c6, a7 + c7};
    float y[8];
    #pragma unroll
    for (int q = 0; q < 8; ++q) {
        float yy = av[q] * di * S.sSc[f0 + q] + S.sSh[f0 + q];
        y[q] = (yy >= 0.f) ? yy : NEG_SLOPE * yy;
    }
    int g0 = batch[vb * 64];
    if (valid) {
        int g = batch[node];
        int slot = g - g0;
        if (slot < 16) {
            #pragma unroll
            for (int q = 0; q < 8; ++q) atomicAdd(&S.sAcc[slot][f0 + q], y[q]);
            if (fq == 0) atomicAdd(&S.sCnt[slot], 1);
        } else {
            #pragma unroll
            for (int q = 0; q < 8; ++q) atomicAdd(&out[(g << 5) + f0 + q], y[q]);
            if (fq == 0) atomicAdd(&gcnt[g], 1.f);
        }
    }
    __syncthreads();
    for (int i = tid; i < 16 * 32; i += 256) {
        int s = i >> 5;
        if (S.sCnt[s] > 0)
            atomicAdd(&out[((g0 + s) << 5) + (i & 31)], ((float*)S.sAcc)[i]);
    }
    if (tid < 16 && S.sCnt[tid] > 0)
        atomicAdd(&gcnt[g0 + tid], (float)S.sCnt[tid]);
    __syncthreads();
}

// ===================== fallback standalone layer kernels =====================
__global__ void __launch_bounds__(256) layer1_gemm2_kernel(
        const float4* __restrict__ xs, const int* __restrict__ rowptr,
        const int* __restrict__ cnt, const int* __restrict__ eidx,
        const float* __restrict__ dinv, const float* __restrict__ W1,
        const float* __restrict__ b1, const float* __restrict__ g1,
        const float* __restrict__ be1, const float* __restrict__ rm1,
        const float* __restrict__ rv1, const float* __restrict__ W2,
        uint32_t* __restrict__ Tp, int N) {
    __shared__ SL1 S;
    for (int i = threadIdx.x; i < 64 * 64; i += 256) S.sW2[i] = W2[i];
    if (threadIdx.x < 192) S.sW1[threadIdx.x] = W1[threadIdx.x];
    if (threadIdx.x < 64) {
        int f = threadIdx.x;
        float sc = rsqrtf(rv1[f] + EPS_BN) * g1[f];
        S.sSc[f] = sc;
        S.sSh[f] = (b1[f] - rm1[f]) * sc + be1[f];
    }
    __syncthreads();
    layer1_body(S, blockIdx.x, xs, rowptr, cnt, eidx, dinv, Tp, N);
}

__global__ void __launch_bounds__(256) layer2_gather_gemm3_kernel(
        const uint32_t* __restrict__ Tp, const int* __restrict__ rowptr,
        const int* __restrict__ cnt, const int* __restrict__ eidx,
        const float* __restrict__ dinv,
        const float* __restrict__ b2, const float* __restrict__ g2,
        const float* __restrict__ be2, const float* __restrict__ rm2,
        const float* __restrict__ rv2, const float* __restrict__ W3,
        uint32_t* __restrict__ Tp2, int N) {
    __shared__ SL2 S;
    for (int i = threadIdx.x; i < 64 * 32; i += 256) S.sW3[i] = W3[i];
    if (threadIdx.x < 64) {
        int f = threadIdx.x;
        float sc = rsqrtf(rv2[f] + EPS_BN) * g2[f];
        S.sSc[f] = sc;
        S.sSh[f] = (b2[f] - rm2[f]) * sc + be2[f];
    }
    __syncthreads();
    layer2_body(S, blockIdx.x, Tp, rowptr, cnt, eidx, dinv, Tp2, N);
}

__global__ void __launch_bounds__(256) layer3_gather_pool_kernel(
        const uint32_t* __restrict__ Tp2, const int* __restrict__ rowptr,
        const int* __restrict__ cnt, const int* __restrict__ eidx,
        const float* __restrict__ dinv, const int* __restrict__ batch,
        const float* __restrict__ b3, const float* __restrict__ g3,
        const float* __restrict__ be3, const float* __restrict__ rm3,
        const float* __restrict__ rv3,
        float* __restrict__ out, float* __restrict__ gcnt, int N) {
    __shared__ SL3 S;
    if (threadIdx.x < 32) {
        int f = threadIdx.x;
        float sc = rsqrtf(rv3[f] + EPS_BN) * g3[f];
        S.sSc[f] = sc;
        S.sSh[f] = (b3[f] - rm3[f]) * sc + be3[f];
    }
    __syncthreads();
    layer3_body(S, blockIdx.x, Tp2, rowptr, cnt, eidx, dinv, batch, out, gcnt, N);
}

__global__ void pool_div_kernel(float* __restrict__ out, const float* __restrict__ gcnt, int G) {
    int tid = blockIdx.x * blockDim.x + threadIdx.x;
    if (tid < (G << 5)) out[tid] /= fmaxf(gcnt[tid >> 5], 1.0f);
}

// ===================== cooperative mega kernel =====================
struct MegaParams {
    const int* src; const int* dst; const float* x; const int* batch;
    const float *W1, *b1, *g1, *be1, *rm1, *rv1, *W2;
    const float *b2, *g2, *be2, *rm2, *rv2, *W3;
    const float *b3, *g3, *be3, *rm3, *rv3;
    int* gcur; uint32_t* staged;
    int* rowptr; int* cnt; float* dinv; float4* xs; int* eidx;
    uint32_t* Tp; uint32_t* Tp2; float* gcnt; float* out;
    int N, E, G, nbins, cap, chunk;
};

struct SStage { uint32_t bbuf[NBINS_LDS][BUFCAP]; int bcnt[NBINS_LDS]; int gpos[NBINS_LDS]; };
struct SFill  { int lcnt[BINSIZE]; int loff[BINSIZE]; int ps[256]; };
union SMem { SStage st; SFill fi; SL1 l1; SL2 l2; SL3 l3; };

__global__ void __launch_bounds__(NTHR, 4) mega_coop_kernel(MegaParams p) {
    __shared__ SMem sm;
    cg::grid_group grid = cg::this_grid();
    const int tid = threadIdx.x;

    // ---- P1: zero out/gcnt + stage multisplit ----
    for (int i = blockIdx.x * NTHR + tid; i < p.G * 33; i += NBLK * NTHR) {
        if (i < p.G * 32) p.out[i] = 0.f; else p.gcnt[i - p.G * 32] = 0.f;
    }
    {
        SStage& S = sm.st;
        for (int i = tid; i < p.nbins; i += NTHR) S.bcnt[i] = 0;
        __syncthreads();
        int e0 = blockIdx.x * p.chunk;
        int e1 = min(e0 + p.chunk, p.E);
        for (int base = e0; base < e1; base += NTHR * 4) {
            int e = base + tid * 4;
            int s0, s1, s2, s3, d0, d1, d2, d3;
            int ne = 0;
            if (e + 4 <= e1) {
                int4 s4 = *(const int4*)(p.src + e);
                int4 d4 = *(const int4*)(p.dst + e);
                s0 = s4.x; s1 = s4.y; s2 = s4.z; s3 = s4.w;
                d0 = d4.x; d1 = d4.y; d2 = d4.z; d3 = d4.w;
                ne = 4;
            } else {
                int k = 0;
                for (; e + k < e1 && k < 4; ++k) {
                    int sv = p.src[e + k], dv = p.dst[e + k];
                    if (k == 0) { s0 = sv; d0 = dv; }
                    else if (k == 1) { s1 = sv; d1 = dv; }
                    else if (k == 2) { s2 = sv; d2 = dv; }
                    else { s3 = sv; d3 = dv; }
                }
                ne = k;
            }
            #pragma unroll
            for (int k = 0; k < 4; ++k) {
                if (k >= ne) break;
                int s = (k == 0) ? s0 : (k == 1) ? s1 : (k == 2) ? s2 : s3;
                int d = (k == 0) ? d0 : (k == 1) ? d1 : (k == 2) ? d2 : d3;
                int bin = d >> BINSHIFT;
                uint32_t rec = ((uint32_t)s << BINSHIFT) | (uint32_t)(d & (BINSIZE - 1));
                int pos = atomicAdd(&S.bcnt[bin], 1);
                if (pos < BUFCAP) S.bbuf[bin][pos] = rec;
                else {
                    int gp = atomicAdd(&p.gcur[bin * GSTRIDE], 1);
                    p.staged[(size_t)bin * p.cap + gp] = rec;
                }
            }
        }
        __syncthreads();
        for (int b = tid; b < p.nbins; b += NTHR) {
            int c = min(S.bcnt[b], BUFCAP);
            S.gpos[b] = (c > 0) ? atomicAdd(&p.gcur[b * GSTRIDE], c) : 0;
        }
        __syncthreads();
        int grp = tid >> 4, lane16 = tid & 15;
        for (int b = grp; b < p.nbins; b += 16) {
            int c = min(S.bcnt[b], BUFCAP);
            int gp = S.gpos[b];
            for (int i = lane16; i < c; i += 16)
                p.staged[(size_t)b * p.cap + gp + i] = S.bbuf[b][i];
        }
    }
    grid.sync();

    // ---- P2: per-bin CSR fill ----
    if (blockIdx.x < p.nbins) {
        SFill& S = sm.fi;
        int bin = blockIdx.x;
        int v = (tid < p.nbins && tid < bin) ? p.gcur[tid * GSTRIDE] : 0;
        S.ps[tid] = v;
        __syncthreads();
        for (int off = 128; off; off >>= 1) {
            if (tid < off) S.ps[tid] += S.ps[tid + off];
            __syncthreads();
        }
        int bb = S.ps[0];
        __syncthreads();
        int node0 = bin << BINSHIFT;
        int nn = min(BINSIZE, p.N - node0);
        int nrec = p.gcur[bin * GSTRIDE];
        const uint32_t* recs = p.staged + (size_t)bin * p.cap;
        for (int i = tid; i < BINSIZE; i += NTHR) S.lcnt[i] = 0;
        __syncthreads();
        for (int t = tid; t < nrec; t += NTHR)
            atomicAdd(&S.lcnt[recs[t] & (BINSIZE - 1)], 1);
        __syncthreads();
        int p0 = S.lcnt[2 * tid], p1 = S.lcnt[2 * tid + 1];
        int pv = p0 + p1;
        S.ps[tid] = pv;
        __syncthreads();
        for (int off = 1; off < 256; off <<= 1) {
            int t = (tid >= off) ? S.ps[tid - off] : 0;
            __syncthreads();
            S.ps[tid] += t;
            __syncthreads();
        }
        int base = S.ps[tid] - pv;
        S.loff[2 * tid] = base;
        S.loff[2 * tid + 1] = base + p0;
        __syncthreads();
        for (int i = tid; i < nn; i += NTHR) {
            int node = node0 + i;
            p.rowptr[node] = bb + S.loff[i];
            p.cnt[node] = S.lcnt[i];
            float di = rsqrtf((float)(S.lcnt[i] + 1));
            p.dinv[node] = di;
            const float* xr = p.x + (size_t)node * 3;
            p.xs[node] = make_float4(xr[0] * di, xr[1] * di, xr[2] * di, 0.f);
            S.lcnt[i] = 0;
        }
        __syncthreads();
        for (int t = tid; t < nrec; t += NTHR) {
            uint32_t r = recs[t];
            int li = r & (BINSIZE - 1);
            int pp = atomicAdd(&S.lcnt[li], 1);
            p.eidx[bb + S.loff[li] + pp] = (int)(r >> BINSHIFT);
        }
    }
    grid.sync();

    // ---- P3: layer1 + GEMM W2 ----
    {
        SL1& S = sm.l1;
        for (int i = tid; i < 64 * 64; i += NTHR) S.sW2[i] = p.W2[i];
        if (tid < 192) S.sW1[tid] = p.W1[tid];
        if (tid < 64) {
            float sc = rsqrtf(p.rv1[tid] + EPS_BN) * p.g1[tid];
            S.sSc[tid] = sc;
            S.sSh[tid] = (p.b1[tid] - p.rm1[tid]) * sc + p.be1[tid];
        }
        __syncthreads();
        const int NV = (p.N + 31) / 32;
        for (int vb = blockIdx.x; vb < NV; vb += NBLK) {
            layer1_body(S, vb, p.xs, p.rowptr, p.cnt, p.eidx, p.dinv, p.Tp, p.N);
            __syncthreads();
        }
    }
    grid.sync();

    // ---- P4: layer2 + GEMM W3 ----
    {
        SL2& S = sm.l2;
        for (int i = tid; i < 64 * 32; i += NTHR) S.sW3[i] = p.W3[i];
        if (tid < 64) {
            float sc = rsqrtf(p.rv2[tid] + EPS_BN) * p.g2[tid];
            S.sSc[tid] = sc;
            S.sSh[tid] = (p.b2[tid] - p.rm2[tid]) * sc + p.be2[tid];
        }
        __syncthreads();
        const int NV = (p.N + 31) / 32;
        for (int vb = blockIdx.x; vb < NV; vb += NBLK) {
            layer2_body(S, vb, p.Tp, p.rowptr, p.cnt, p.eidx, p.dinv, p.Tp2, p.N);
            __syncthreads();
        }
    }
    grid.sync();

    // ---- P5: layer3 + pool ----
    {
        SL3& S = sm.l3;
        if (tid < 32) {
            float sc = rsqrtf(p.rv3[tid] + EPS_BN) * p.g3[tid];
            S.sSc[tid] = sc;
            S.sSh[tid] = (p.b3[tid] - p.rm3[tid]) * sc + p.be3[tid];
        }
        __syncthreads();
        const int NV = (p.N + 63) / 64;
        for (int vb = blockIdx.x; vb < NV; vb += NBLK) {
            layer3_body(S, vb, p.Tp2, p.rowptr, p.cnt, p.eidx, p.dinv, p.batch,
                        p.out, p.gcnt, p.N);
        }
    }
    grid.sync();

    // ---- P6: pool divide ----
    for (int t = blockIdx.x * NTHR + tid; t < (p.G << 5); t += NBLK * NTHR)
        p.out[t] /= fmaxf(p.gcnt[t >> 5], 1.0f);
}

extern "C" void kernel_launch(void* const* d_in, const int* in_sizes, int n_in,
                              void* d_out, int out_size, void* d_ws, size_t ws_size,
                              hipStream_t stream) {
    const float* x   = (const float*)d_in[0];
    const float* W1  = (const float*)d_in[1];
    const float* b1  = (const float*)d_in[2];
    const float* g1  = (const float*)d_in[3];
    const float* be1 = (const float*)d_in[4];
    const float* rm1 = (const float*)d_in[5];
    const float* rv1 = (const float*)d_in[6];
    const float* W2  = (const float*)d_in[7];
    const float* b2  = (const float*)d_in[8];
    const float* g2  = (const float*)d_in[9];
    const float* be2 = (const float*)d_in[10];
    const float* rm2 = (const float*)d_in[11];
    const float* rv2 = (const float*)d_in[12];
    const float* W3  = (const float*)d_in[13];
    const float* b3  = (const float*)d_in[14];
    const float* g3  = (const float*)d_in[15];
    const float* be3 = (const float*)d_in[16];
    const float* rm3 = (const float*)d_in[17];
    const float* rv3 = (const float*)d_in[18];
    const int* ei    = (const int*)d_in[19];
    const int* batch = (const int*)d_in[20];

    const int N = in_sizes[0] / 3;
    const int E = in_sizes[19] / 2;
    const int G = out_size / 32;
    const int* src = ei;
    const int* dst = ei + E;

    const int nbins = (N + BINSIZE - 1) >> BINSHIFT;
    const int cap = (((E / nbins) * 3) / 2 + 15) & ~15;

    int*      gcur    = (int*)d_ws;
    int*      cnt     = gcur + 256 * GSTRIDE;
    float*    dinv    = (float*)(cnt + N);
    int*      rowptr  = (int*)(dinv + N);
    int*      eidx    = rowptr + N;
    float4*   xs      = (float4*)(((uintptr_t)(eidx + E) + 15) & ~(uintptr_t)15);
    uint32_t* Tp      = (uint32_t*)(xs + N);
    uint32_t* Tp2     = Tp + (size_t)N * 32;
    float*    gcnt    = (float*)(Tp2 + (size_t)N * 16);
    uint32_t* staged  = Tp;                               // alias: dead before Tp written
    float*    out     = (float*)d_out;

    hipMemsetAsync(gcur, 0, 256 * GSTRIDE * 4, stream);

    // ---- try cooperative mega kernel (guide §1: supported by harness) ----
    const int coop_chunk = (((E + NBLK - 1) / NBLK) + 3) & ~3;
    MegaParams mp;
    mp.src = src; mp.dst = dst; mp.x = x; mp.batch = batch;
    mp.W1 = W1; mp.b1 = b1; mp.g1 = g1; mp.be1 = be1; mp.rm1 = rm1; mp.rv1 = rv1; mp.W2 = W2;
    mp.b2 = b2; mp.g2 = g2; mp.be2 = be2; mp.rm2 = rm2; mp.rv2 = rv2; mp.W3 = W3;
    mp.b3 = b3; mp.g3 = g3; mp.be3 = be3; mp.rm3 = rm3; mp.rv3 = rv3;
    mp.gcur = gcur; mp.staged = staged;
    mp.rowptr = rowptr; mp.cnt = cnt; mp.dinv = dinv; mp.xs = xs; mp.eidx = eidx;
    mp.Tp = Tp; mp.Tp2 = Tp2; mp.gcnt = gcnt; mp.out = out;
    mp.N = N; mp.E = E; mp.G = G; mp.nbins = nbins; mp.cap = cap; mp.chunk = coop_chunk;
    void* args[] = { &mp };
    hipError_t err = hipLaunchCooperativeKernel((const void*)mega_coop_kernel,
                                                dim3(NBLK), dim3(NTHR), args, 0, stream);
    if (err == hipSuccess) return;

    // ---- fallback: proven R8 7-dispatch pipeline ----
    const int B = 256;
    const int STAGE_BLOCKS = 512;
    const int chunk = (((E + STAGE_BLOCKS - 1) / STAGE_BLOCKS) + 3) & ~3;
    stage_ms_kernel<<<STAGE_BLOCKS, 256, 0, stream>>>(src, dst, gcur, staged, cap, nbins, E, chunk);
    fill_csr_kernel<<<nbins, 256, 0, stream>>>(staged, gcur, x, cap, nbins,
                                               rowptr, cnt, dinv, xs, eidx, N, out, gcnt, G);
    layer1_gemm2_kernel<<<(N + 31) / 32, 256, 0, stream>>>(
        xs, rowptr, cnt, eidx, dinv, W1, b1, g1, be1, rm1, rv1, W2, Tp, N);
    layer2_gather_gemm3_kernel<<<(N + 31) / 32, 256, 0, stream>>>(
        Tp, rowptr, cnt, eidx, dinv, b2, g2, be2, rm2, rv2, W3, Tp2, N);
    layer3_gather_pool_kernel<<<(N + 63) / 64, 256, 0, stream>>>(
        Tp2, rowptr, cnt, eidx, dinv, batch, b3, g3, be3, rm3, rv3, out, gcnt, N);
    pool_div_kernel<<<(G * 32 + B - 1) / B, B, 0, stream>>>(out, gcnt, G);
}

// Round 10
// 252.490 us; speedup vs baseline: 2.6690x; 2.6690x over previous
//
#include <hip/hip_runtime.h>

#define EPS_BN 1e-5f
#define NEG_SLOPE 0.01f

#define BINSHIFT 9                 // 512 nodes per bin (BINSHIFT 7 regressed: R3)
#define BINSIZE (1 << BINSHIFT)
#define NBINS_LDS 200              // supports N up to 102400
#define BUFCAP 24                  // LDS records per (block,bin)
#define GSTRIDE 16                 // gcur padding: one counter per 64B line

// ---- bf16x2 pack/unpack (RNE) ----
__device__ __forceinline__ uint32_t pack2_bf16(float x, float y) {
    uint32_t ux = __float_as_uint(x);
    uint32_t uy = __float_as_uint(y);
    ux = (ux + 0x7fffu + ((ux >> 16) & 1u)) >> 16;
    uy = (uy + 0x7fffu + ((uy >> 16) & 1u)) >> 16;
    return (uy << 16) | (ux & 0xffffu);
}
__device__ __forceinline__ float bf_lo(uint32_t p) { return __uint_as_float(p << 16); }
__device__ __forceinline__ float bf_hi(uint32_t p) { return __uint_as_float(p & 0xffff0000u); }

// ---- phase A: LDS multisplit; 4 edges/thread/iter; packed 4-B records ----
__global__ void __launch_bounds__(256) stage_ms_kernel(
        const int* __restrict__ src, const int* __restrict__ dst,
        int* __restrict__ gcur, uint32_t* __restrict__ staged,
        int cap, int nbins, int E, int chunk) {
    __shared__ uint32_t bbuf[NBINS_LDS][BUFCAP];
    __shared__ int bcnt[NBINS_LDS];
    __shared__ int gpos[NBINS_LDS];
    for (int i = threadIdx.x; i < nbins; i += 256) bcnt[i] = 0;
    __syncthreads();
    int e0 = blockIdx.x * chunk;
    int e1 = min(e0 + chunk, E);
    for (int base = e0; base < e1; base += 1024) {       // 256 threads x 4 edges
        int e = base + threadIdx.x * 4;
        int s0, s1, s2, s3, d0, d1, d2, d3;
        int ne = 0;
        if (e + 4 <= e1) {
            int4 s4 = *(const int4*)(src + e);
            int4 d4 = *(const int4*)(dst + e);
            s0 = s4.x; s1 = s4.y; s2 = s4.z; s3 = s4.w;
            d0 = d4.x; d1 = d4.y; d2 = d4.z; d3 = d4.w;
            ne = 4;
        } else {
            int k = 0;
            for (; e + k < e1 && k < 4; ++k) {
                int sv = src[e + k], dv = dst[e + k];
                if (k == 0) { s0 = sv; d0 = dv; }
                else if (k == 1) { s1 = sv; d1 = dv; }
                else if (k == 2) { s2 = sv; d2 = dv; }
                else { s3 = sv; d3 = dv; }
            }
            ne = k;
        }
        #pragma unroll
        for (int k = 0; k < 4; ++k) {
            if (k >= ne) break;
            int s = (k == 0) ? s0 : (k == 1) ? s1 : (k == 2) ? s2 : s3;
            int d = (k == 0) ? d0 : (k == 1) ? d1 : (k == 2) ? d2 : d3;
            int bin = d >> BINSHIFT;
            uint32_t rec = ((uint32_t)s << BINSHIFT) | (uint32_t)(d & (BINSIZE - 1));
            int pos = atomicAdd(&bcnt[bin], 1);
            if (pos < BUFCAP) {
                bbuf[bin][pos] = rec;
            } else {                                     // rare: direct global append
                int gp = atomicAdd(&gcur[bin * GSTRIDE], 1);
                staged[(size_t)bin * cap + gp] = rec;
            }
        }
    }
    __syncthreads();
    // drain phase 1: one bin per THREAD -> all global atomics issue concurrently
    for (int b = threadIdx.x; b < nbins; b += 256) {
        int c = min(bcnt[b], BUFCAP);
        gpos[b] = (c > 0) ? atomicAdd(&gcur[b * GSTRIDE], c) : 0;
    }
    __syncthreads();
    // drain phase 2: cooperative 16-lane copy per bin
    int grp = threadIdx.x >> 4, lane = threadIdx.x & 15;
    for (int b = grp; b < nbins; b += 16) {
        int c = min(bcnt[b], BUFCAP);
        int gp = gpos[b];
        for (int i = lane; i < c; i += 16)
            staged[(size_t)b * cap + gp + i] = bbuf[b][i];
    }
}

// ---- phase B: per-bin CSR fill + rowptr/cnt/dinv/xs (packed recs) ----
__global__ void __launch_bounds__(256) fill_csr_kernel(
        const uint32_t* __restrict__ staged, const int* __restrict__ gcur,
        const float* __restrict__ x, int cap, int nbins,
        int* __restrict__ rowptr, int* __restrict__ cnt,
        float* __restrict__ dinv, float4* __restrict__ xs,
        int* __restrict__ eidx, int N,
        float* __restrict__ out, float* __restrict__ gcnt, int G) {
    __shared__ int lcnt[BINSIZE];
    __shared__ int loff[BINSIZE];
    __shared__ int ps[256];
    int bin = blockIdx.x;
    // ---- binbase = sum of gcur[i] for i < bin ----
    int v = (threadIdx.x < nbins && threadIdx.x < bin) ? gcur[threadIdx.x * GSTRIDE] : 0;
    ps[threadIdx.x] = v;
    __syncthreads();
    for (int off = 128; off; off >>= 1) {
        if (threadIdx.x < off) ps[threadIdx.x] += ps[threadIdx.x + off];
        __syncthreads();
    }
    int bb = ps[0];
    __syncthreads();
    // ---- block 0: zero pool accumulators ----
    if (bin == 0) {
        for (int i = threadIdx.x; i < G * 32; i += 256) out[i] = 0.f;
        for (int i = threadIdx.x; i < G; i += 256) gcnt[i] = 0.f;
    }
    int node0 = bin << BINSHIFT;
    int nn = min(BINSIZE, N - node0);
    int nrec = gcur[bin * GSTRIDE];
    const uint32_t* recs = staged + (size_t)bin * cap;
    for (int i = threadIdx.x; i < BINSIZE; i += 256) lcnt[i] = 0;
    __syncthreads();
    for (int t = threadIdx.x; t < nrec; t += 256)
        atomicAdd(&lcnt[recs[t] & (BINSIZE - 1)], 1);
    __syncthreads();
    int p0 = lcnt[2 * threadIdx.x], p1 = lcnt[2 * threadIdx.x + 1];
    int pv = p0 + p1;
    ps[threadIdx.x] = pv;
    __syncthreads();
    for (int off = 1; off < 256; off <<= 1) {
        int t = (threadIdx.x >= off) ? ps[threadIdx.x - off] : 0;
        __syncthreads();
        ps[threadIdx.x] += t;
        __syncthreads();
    }
    int base = ps[threadIdx.x] - pv;
    loff[2 * threadIdx.x] = base;
    loff[2 * threadIdx.x + 1] = base + p0;
    __syncthreads();
    for (int i = threadIdx.x; i < nn; i += 256) {
        int node = node0 + i;
        rowptr[node] = bb + loff[i];
        cnt[node] = lcnt[i];
        float di = rsqrtf((float)(lcnt[i] + 1));         // +1 self-loop
        dinv[node] = di;
        const float* xr = x + (size_t)node * 3;
        xs[node] = make_float4(xr[0] * di, xr[1] * di, xr[2] * di, 0.f);
        lcnt[i] = 0;                                     // reuse as cursor
    }
    __syncthreads();
    for (int t = threadIdx.x; t < nrec; t += 256) {
        uint32_t r = recs[t];
        int li = r & (BINSIZE - 1);
        int p = atomicAdd(&lcnt[li], 1);
        eidx[bb + loff[li] + p] = (int)(r >> BINSHIFT);  // block-private range
    }
}

// ---- fused layer1 + GEMM(64->64) + dinv-scale + bf16 pack.
// R10: W2 NOT staged in LDS -- read directly in the FMA loop (16KB, L1-hits
// after first block per CU). Removes 3125x16KB startup loads + drops LDS
// 25.4->9.6KB: occupancy 4->8 blocks/CU. FMA order unchanged (bit-identical).
__global__ void __launch_bounds__(256) layer1_gemm2_kernel(
        const float4* __restrict__ xs, const int* __restrict__ rowptr,
        const int* __restrict__ cnt, const int* __restrict__ eidx,
        const float* __restrict__ dinv, const float* __restrict__ W1,
        const float* __restrict__ b1, const float* __restrict__ g1,
        const float* __restrict__ be1, const float* __restrict__ rm1,
        const float* __restrict__ rv1, const float* __restrict__ W2,
        uint32_t* __restrict__ Tp, int N) {
    __shared__ float sW1[3 * 64];
    __shared__ float sSc[64], sSh[64];
    __shared__ float sH[32][64];
    __shared__ float sDinv[32];
    if (threadIdx.x < 192) sW1[threadIdx.x] = W1[threadIdx.x];
    if (threadIdx.x < 64) {
        int f = threadIdx.x;
        float sc = rsqrtf(rv1[f] + EPS_BN) * g1[f];
        sSc[f] = sc;
        sSh[f] = (b1[f] - rm1[f]) * sc + be1[f];
    }
    __syncthreads();
    int lane = threadIdx.x & 7;
    int nl = threadIdx.x >> 3;                           // 0..31
    int node = blockIdx.x * 32 + nl;
    int m = min(node, N - 1);                            // clamp; no early return (sync below)
    int start = rowptr[m], deg = cnt[m];
    float ax = 0.f, ay = 0.f, az = 0.f;
    for (int j = lane; j < deg; j += 8) {
        float4 v = xs[eidx[start + j]];
        ax += v.x; ay += v.y; az += v.z;
    }
    #pragma unroll
    for (int o = 4; o; o >>= 1) {
        ax += __shfl_xor(ax, o, 8);
        ay += __shfl_xor(ay, o, 8);
        az += __shfl_xor(az, o, 8);
    }
    float4 self = xs[m];
    float di = dinv[m];
    float gx = (ax + self.x) * di, gy = (ay + self.y) * di, gz = (az + self.z) * di;
    if (lane == 0) sDinv[nl] = di;
    int f0 = lane * 8;
    #pragma unroll
    for (int hh = 0; hh < 2; ++hh) {
        float4 hv;
        #pragma unroll
        for (int q = 0; q < 4; ++q) {
            int f = f0 + 4 * hh + q;
            float a = gx * sW1[f] + gy * sW1[64 + f] + gz * sW1[128 + f];
            float y = a * sSc[f] + sSh[f];
            ((float*)&hv)[q] = (y >= 0.f) ? y : NEG_SLOPE * y;
        }
        *(float4*)&sH[nl][f0 + 4 * hh] = hv;
    }
    __syncthreads();
    int fp = threadIdx.x & 31;                           // feature pair 0..31
    int ng = threadIdx.x >> 5;                           // 0..7
    const float2* w2 = (const float2*)W2 + fp;           // global, L1-cached (16KB)
    const float4* sH0 = (const float4*)&sH[ng][0];
    const float4* sH1 = (const float4*)&sH[ng + 8][0];
    const float4* sH2 = (const float4*)&sH[ng + 16][0];
    const float4* sH3 = (const float4*)&sH[ng + 24][0];
    float a00 = 0.f, a01 = 0.f, a10 = 0.f, a11 = 0.f;
    float a20 = 0.f, a21 = 0.f, a30 = 0.f, a31 = 0.f;
    #pragma unroll 4
    for (int k4 = 0; k4 < 16; ++k4) {
        float4 h0 = sH0[k4];
        float4 h1 = sH1[k4];
        float4 h2 = sH2[k4];
        float4 h3 = sH3[k4];
        float2 w;
        w = w2[(4 * k4 + 0) * 32];
        a00 = fmaf(h0.x, w.x, a00); a01 = fmaf(h0.x, w.y, a01);
        a10 = fmaf(h1.x, w.x, a10); a11 = fmaf(h1.x, w.y, a11);
        a20 = fmaf(h2.x, w.x, a20); a21 = fmaf(h2.x, w.y, a21);
        a30 = fmaf(h3.x, w.x, a30); a31 = fmaf(h3.x, w.y, a31);
        w = w2[(4 * k4 + 1) * 32];
        a00 = fmaf(h0.y, w.x, a00); a01 = fmaf(h0.y, w.y, a01);
        a10 = fmaf(h1.y, w.x, a10); a11 = fmaf(h1.y, w.y, a11);
        a20 = fmaf(h2.y, w.x, a20); a21 = fmaf(h2.y, w.y, a21);
        a30 = fmaf(h3.y, w.x, a30); a31 = fmaf(h3.y, w.y, a31);
        w = w2[(4 * k4 + 2) * 32];
        a00 = fmaf(h0.z, w.x, a00); a01 = fmaf(h0.z, w.y, a01);
        a10 = fmaf(h1.z, w.x, a10); a11 = fmaf(h1.z, w.y, a11);
        a20 = fmaf(h2.z, w.x, a20); a21 = fmaf(h2.z, w.y, a21);
        a30 = fmaf(h3.z, w.x, a30); a31 = fmaf(h3.z, w.y, a31);
        w = w2[(4 * k4 + 3) * 32];
        a00 = fmaf(h0.w, w.x, a00); a01 = fmaf(h0.w, w.y, a01);
        a10 = fmaf(h1.w, w.x, a10); a11 = fmaf(h1.w, w.y, a11);
        a20 = fmaf(h2.w, w.x, a20); a21 = fmaf(h2.w, w.y, a21);
        a30 = fmaf(h3.w, w.x, a30); a31 = fmaf(h3.w, w.y, a31);
    }
    int base = blockIdx.x * 32;
    int n0 = base + ng, n1 = base + ng + 8, n2 = base + ng + 16, n3 = base + ng + 24;
    if (n0 < N) { float d = sDinv[ng];      Tp[(size_t)n0 * 32 + fp] = pack2_bf16(a00 * d, a01 * d); }
    if (n1 < N) { float d = sDinv[ng + 8];  Tp[(size_t)n1 * 32 + fp] = pack2_bf16(a10 * d, a11 * d); }
    if (n2 < N) { float d = sDinv[ng + 16]; Tp[(size_t)n2 * 32 + fp] = pack2_bf16(a20 * d, a21 * d); }
    if (n3 < N) { float d = sDinv[ng + 24]; Tp[(size_t)n3 * 32 + fp] = pack2_bf16(a30 * d, a31 * d); }
}

// ---- fused layer-2 gather + BN2 + LReLU + GEMM(64->32) + dinv-scale + pack.
// R10: W3 read directly from global (8KB, L1-cached); LDS 17.2->9.2KB.
__global__ void __launch_bounds__(256) layer2_gather_gemm3_kernel(
        const uint32_t* __restrict__ Tp, const int* __restrict__ rowptr,
        const int* __restrict__ cnt, const int* __restrict__ eidx,
        const float* __restrict__ dinv,
        const float* __restrict__ b2, const float* __restrict__ g2,
        const float* __restrict__ be2, const float* __restrict__ rm2,
        const float* __restrict__ rv2, const float* __restrict__ W3,
        uint32_t* __restrict__ Tp2, int N) {
    __shared__ float sSc[64], sSh[64];
    __shared__ float sH[32][64];
    __shared__ float sDinv[32];
    if (threadIdx.x < 64) {
        int f = threadIdx.x;
        float sc = rsqrtf(rv2[f] + EPS_BN) * g2[f];
        sSc[f] = sc;
        sSh[f] = (b2[f] - rm2[f]) * sc + be2[f];
    }
    __syncthreads();
    int fq = threadIdx.x & 7;
    int nl = threadIdx.x >> 3;                           // 0..31
    int node = blockIdx.x * 32 + nl;
    int m = min(node, N - 1);
    const uint4* T4 = (const uint4*)Tp + fq;             // stride 8 uint4 per node
    int start = rowptr[m];
    int deg = cnt[m];
    uint4 ts = T4[(size_t)m * 8];
    float a0 = bf_lo(ts.x), a1 = bf_hi(ts.x), a2 = bf_lo(ts.y), a3 = bf_hi(ts.y);
    float a4 = bf_lo(ts.z), a5 = bf_hi(ts.z), a6 = bf_lo(ts.w), a7 = bf_hi(ts.w);
    float c0 = 0.f, c1 = 0.f, c2 = 0.f, c3 = 0.f;
    float c4 = 0.f, c5 = 0.f, c6 = 0.f, c7 = 0.f;
    const int* ep = eidx + start;
    int j = 0;
    int s0, s1, s2, s3;
    if (deg >= 4) { s0 = ep[0]; s1 = ep[1]; s2 = ep[2]; s3 = ep[3]; }
    for (; j + 8 <= deg; j += 4) {                       // pipelined: prefetch j+4..j+7
        uint4 t0 = T4[(size_t)s0 * 8];
        uint4 t1 = T4[(size_t)s1 * 8];
        uint4 t2 = T4[(size_t)s2 * 8];
        uint4 t3 = T4[(size_t)s3 * 8];
        s0 = ep[j + 4]; s1 = ep[j + 5]; s2 = ep[j + 6]; s3 = ep[j + 7];
        a0 += bf_lo(t0.x) + bf_lo(t2.x);  a1 += bf_hi(t0.x) + bf_hi(t2.x);
        a2 += bf_lo(t0.y) + bf_lo(t2.y);  a3 += bf_hi(t0.y) + bf_hi(t2.y);
        a4 += bf_lo(t0.z) + bf_lo(t2.z);  a5 += bf_hi(t0.z) + bf_hi(t2.z);
        a6 += bf_lo(t0.w) + bf_lo(t2.w);  a7 += bf_hi(t0.w) + bf_hi(t2.w);
        c0 += bf_lo(t1.x) + bf_lo(t3.x);  c1 += bf_hi(t1.x) + bf_hi(t3.x);
        c2 += bf_lo(t1.y) + bf_lo(t3.y);  c3 += bf_hi(t1.y) + bf_hi(t3.y);
        c4 += bf_lo(t1.z) + bf_lo(t3.z);  c5 += bf_hi(t1.z) + bf_hi(t3.z);
        c6 += bf_lo(t1.w) + bf_lo(t3.w);  c7 += bf_hi(t1.w) + bf_hi(t3.w);
    }
    if (j + 4 <= deg) {                                  // drain the prefetched quad
        uint4 t0 = T4[(size_t)s0 * 8];
        uint4 t1 = T4[(size_t)s1 * 8];
        uint4 t2 = T4[(size_t)s2 * 8];
        uint4 t3 = T4[(size_t)s3 * 8];
        a0 += bf_lo(t0.x) + bf_lo(t2.x);  a1 += bf_hi(t0.x) + bf_hi(t2.x);
        a2 += bf_lo(t0.y) + bf_lo(t2.y);  a3 += bf_hi(t0.y) + bf_hi(t2.y);
        a4 += bf_lo(t0.z) + bf_lo(t2.z);  a5 += bf_hi(t0.z) + bf_hi(t2.z);
        a6 += bf_lo(t0.w) + bf_lo(t2.w);  a7 += bf_hi(t0.w) + bf_hi(t2.w);
        c0 += bf_lo(t1.x) + bf_lo(t3.x);  c1 += bf_hi(t1.x) + bf_hi(t3.x);
        c2 += bf_lo(t1.y) + bf_lo(t3.y);  c3 += bf_hi(t1.y) + bf_hi(t3.y);
        c4 += bf_lo(t1.z) + bf_lo(t3.z);  c5 += bf_hi(t1.z) + bf_hi(t3.z);
        c6 += bf_lo(t1.w) + bf_lo(t3.w);  c7 += bf_hi(t1.w) + bf_hi(t3.w);
        j += 4;
    }
    for (; j < deg; ++j) {
        uint4 t0 = T4[(size_t)ep[j] * 8];
        a0 += bf_lo(t0.x); a1 += bf_hi(t0.x);
        a2 += bf_lo(t0.y); a3 += bf_hi(t0.y);
        a4 += bf_lo(t0.z); a5 += bf_hi(t0.z);
        a6 += bf_lo(t0.w); a7 += bf_hi(t0.w);
    }
    float di = dinv[m];
    if (fq == 0) sDinv[nl] = di;
    int f0 = 8 * fq;
    float av[8] = {a0 + c0, a1 + c1, a2 + c2, a3 + c3,
                   a4 + c4, a5 + c5, a6 + c6, a7 + c7};
    #pragma unroll
    for (int hh = 0; hh < 2; ++hh) {
        float4 hv;
        #pragma unroll
        for (int q = 0; q < 4; ++q) {
            int f = f0 + 4 * hh + q;
            float y = av[4 * hh + q] * di * sSc[f] + sSh[f];
            ((float*)&hv)[q] = (y >= 0.f) ? y : NEG_SLOPE * y;
        }
        *(float4*)&sH[nl][f0 + 4 * hh] = hv;
    }
    __syncthreads();
    int fp = threadIdx.x & 15;                           // feature pair 0..15
    int ng = threadIdx.x >> 4;                           // 0..15
    const float2* w3 = (const float2*)W3 + fp;           // global, L1-cached (8KB)
    const float4* sHA = (const float4*)&sH[ng][0];
    const float4* sHB = (const float4*)&sH[ng + 16][0];
    float p0 = 0.f, p1 = 0.f, q0 = 0.f, q1 = 0.f;
    #pragma unroll 4
    for (int k4 = 0; k4 < 16; ++k4) {
        float4 hA = sHA[k4];
        float4 hB = sHB[k4];
        float2 w;
        w = w3[(4 * k4 + 0) * 16];
        p0 = fmaf(hA.x, w.x, p0); p1 = fmaf(hA.x, w.y, p1);
        q0 = fmaf(hB.x, w.x, q0); q1 = fmaf(hB.x, w.y, q1);
        w = w3[(4 * k4 + 1) * 16];
        p0 = fmaf(hA.y, w.x, p0); p1 = fmaf(hA.y, w.y, p1);
        q0 = fmaf(hB.y, w.x, q0); q1 = fmaf(hB.y, w.y, q1);
        w = w3[(4 * k4 + 2) * 16];
        p0 = fmaf(hA.z, w.x, p0); p1 = fmaf(hA.z, w.y, p1);
        q0 = fmaf(hB.z, w.x, q0); q1 = fmaf(hB.z, w.y, q1);
        w = w3[(4 * k4 + 3) * 16];
        p0 = fmaf(hA.w, w.x, p0); p1 = fmaf(hA.w, w.y, p1);
        q0 = fmaf(hB.w, w.x, q0); q1 = fmaf(hB.w, w.y, q1);
    }
    int base = blockIdx.x * 32;
    int nA = base + ng, nB = base + ng + 16;
    if (nA < N) { float d = sDinv[ng];      Tp2[(size_t)nA * 16 + fp] = pack2_bf16(p0 * d, p1 * d); }
    if (nB < N) { float d = sDinv[ng + 16]; Tp2[(size_t)nB * 16 + fp] = pack2_bf16(q0 * d, q1 * d); }
}

// ---- fused layer-3 gather + BN3 + LReLU + mean-pool accumulate (R8 body) ----
#define SLOTS 16
__global__ void __launch_bounds__(256) layer3_gather_pool_kernel(
        const uint32_t* __restrict__ Tp2, const int* __restrict__ rowptr,
        const int* __restrict__ cnt, const int* __restrict__ eidx,
        const float* __restrict__ dinv, const int* __restrict__ batch,
        const float* __restrict__ b3, const float* __restrict__ g3,
        const float* __restrict__ be3, const float* __restrict__ rm3,
        const float* __restrict__ rv3,
        float* __restrict__ out, float* __restrict__ gcnt, int N) {
    __shared__ float sSc[32], sSh[32];
    __shared__ float sAcc[SLOTS][32];
    __shared__ int sCnt[SLOTS];
    if (threadIdx.x < 32) {
        int f = threadIdx.x;
        float sc = rsqrtf(rv3[f] + EPS_BN) * g3[f];
        sSc[f] = sc;
        sSh[f] = (b3[f] - rm3[f]) * sc + be3[f];
    }
    for (int i = threadIdx.x; i < SLOTS * 32; i += 256) ((float*)sAcc)[i] = 0.f;
    if (threadIdx.x < SLOTS) sCnt[threadIdx.x] = 0;
    __syncthreads();
    int fq = threadIdx.x & 3;
    int nl = threadIdx.x >> 2;                           // 0..63
    int node = blockIdx.x * 64 + nl;
    bool valid = node < N;
    int m = valid ? node : N - 1;
    const uint4* T4 = (const uint4*)Tp2 + fq;            // stride 4 uint4 per node
    int start = rowptr[m];
    int deg = cnt[m];
    uint4 ts = T4[(size_t)m * 4];
    float a0 = bf_lo(ts.x), a1 = bf_hi(ts.x), a2 = bf_lo(ts.y), a3 = bf_hi(ts.y);
    float a4 = bf_lo(ts.z), a5 = bf_hi(ts.z), a6 = bf_lo(ts.w), a7 = bf_hi(ts.w);
    float c0 = 0.f, c1 = 0.f, c2 = 0.f, c3 = 0.f;
    float c4 = 0.f, c5 = 0.f, c6 = 0.f, c7 = 0.f;
    const int* ep = eidx + start;
    int j = 0;
    int s0, s1, s2, s3;
    if (deg >= 4) { s0 = ep[0]; s1 = ep[1]; s2 = ep[2]; s3 = ep[3]; }
    for (; j + 8 <= deg; j += 4) {                       // pipelined: prefetch j+4..j+7
        uint4 t0 = T4[(size_t)s0 * 4];
        uint4 t1 = T4[(size_t)s1 * 4];
        uint4 t2 = T4[(size_t)s2 * 4];
        uint4 t3 = T4[(size_t)s3 * 4];
        s0 = ep[j + 4]; s1 = ep[j + 5]; s2 = ep[j + 6]; s3 = ep[j + 7];
        a0 += bf_lo(t0.x) + bf_lo(t2.x);  a1 += bf_hi(t0.x) + bf_hi(t2.x);
        a2 += bf_lo(t0.y) + bf_lo(t2.y);  a3 += bf_hi(t0.y) + bf_hi(t2.y);
        a4 += bf_lo(t0.z) + bf_lo(t2.z);  a5 += bf_hi(t0.z) + bf_hi(t2.z);
        a6 += bf_lo(t0.w) + bf_lo(t2.w);  a7 += bf_hi(t0.w) + bf_hi(t2.w);
        c0 += bf_lo(t1.x) + bf_lo(t3.x);  c1 += bf_hi(t1.x) + bf_hi(t3.x);
        c2 += bf_lo(t1.y) + bf_lo(t3.y);  c3 += bf_hi(t1.y) + bf_hi(t3.y);
        c4 += bf_lo(t1.z) + bf_lo(t3.z);  c5 += bf_hi(t1.z) + bf_hi(t3.z);
        c6 += bf_lo(t1.w) + bf_lo(t3.w);  c7 += bf_hi(t1.w) + bf_hi(t3.w);
    }
    if (j + 4 <= deg) {                                  // drain the prefetched quad
        uint4 t0 = T4[(size_t)s0 * 4];
        uint4 t1 = T4[(size_t)s1 * 4];
        uint4 t2 = T4[(size_t)s2 * 4];
        uint4 t3 = T4[(size_t)s3 * 4];
        a0 += bf_lo(t0.x) + bf_lo(t2.x);  a1 += bf_hi(t0.x) + bf_hi(t2.x);
        a2 += bf_lo(t0.y) + bf_lo(t2.y);  a3 += bf_hi(t0.y) + bf_hi(t2.y);
        a4 += bf_lo(t0.z) + bf_lo(t2.z);  a5 += bf_hi(t0.z) + bf_hi(t2.z);
        a6 += bf_lo(t0.w) + bf_lo(t2.w);  a7 += bf_hi(t0.w) + bf_hi(t2.w);
        c0 += bf_lo(t1.x) + bf_lo(t3.x);  c1 += bf_hi(t1.x) + bf_hi(t3.x);
        c2 += bf_lo(t1.y) + bf_lo(t3.y);  c3 += bf_hi(t1.y) + bf_hi(t3.y);
        c4 += bf_lo(t1.z) + bf_lo(t3.z);  c5 += bf_hi(t1.z) + bf_hi(t3.z);
        c6 += bf_lo(t1.w) + bf_lo(t3.w);  c7 += bf_hi(t1.w) + bf_hi(t3.w);
        j += 4;
    }
    for (; j < deg; ++j) {
        uint4 t0 = T4[(size_t)ep[j] * 4];
        a0 += bf_lo(t0.x); a1 += bf_hi(t0.x);
        a2 += bf_lo(t0.y); a3 += bf_hi(t0.y);
        a4 += bf_lo(t0.z); a5 += bf_hi(t0.z);
        a6 += bf_lo(t0.w); a7 += bf_hi(t0.w);
    }
    float di = dinv[m];
    int f0 = 8 * fq;
    float av[8] = {a0 + c0, a1 + c1, a2 + c2, a3 + c3,
                   a4 + c4, a5 + c5, a6 + c6, a7 + c7};
    float y[8];
    #pragma unroll
    for (int q = 0; q < 8; ++q) {
        float yy = av[q] * di * sSc[f0 + q] + sSh[f0 + q];
        y[q] = (yy >= 0.f) ? yy : NEG_SLOPE * yy;
    }
    int g0 = batch[blockIdx.x * 64];                     // first node of block, always < N
    if (valid) {
        int g = batch[node];
        int slot = g - g0;
        if (slot < SLOTS) {
            #pragma unroll
            for (int q = 0; q < 8; ++q) atomicAdd(&sAcc[slot][f0 + q], y[q]);
            if (fq == 0) atomicAdd(&sCnt[slot], 1);
        } else {                                         // rare: block spans many graphs
            #pragma unroll
            for (int q = 0; q < 8; ++q) atomicAdd(&out[(g << 5) + f0 + q], y[q]);
            if (fq == 0) atomicAdd(&gcnt[g], 1.f);
        }
    }
    __syncthreads();
    for (int i = threadIdx.x; i < SLOTS * 32; i += 256) {
        int s = i >> 5;
        if (sCnt[s] > 0)
            atomicAdd(&out[((g0 + s) << 5) + (i & 31)], ((float*)sAcc)[i]);
    }
    if (threadIdx.x < SLOTS && sCnt[threadIdx.x] > 0)
        atomicAdd(&gcnt[g0 + threadIdx.x], (float)sCnt[threadIdx.x]);
}

__global__ void pool_div_kernel(float* __restrict__ out, const float* __restrict__ gcnt, int G) {
    int tid = blockIdx.x * blockDim.x + threadIdx.x;
    if (tid < (G << 5)) out[tid] /= fmaxf(gcnt[tid >> 5], 1.0f);
}

extern "C" void kernel_launch(void* const* d_in, const int* in_sizes, int n_in,
                              void* d_out, int out_size, void* d_ws, size_t ws_size,
                              hipStream_t stream) {
    const float* x   = (const float*)d_in[0];
    const float* W1  = (const float*)d_in[1];
    const float* b1  = (const float*)d_in[2];
    const float* g1  = (const float*)d_in[3];
    const float* be1 = (const float*)d_in[4];
    const float* rm1 = (const float*)d_in[5];
    const float* rv1 = (const float*)d_in[6];
    const float* W2  = (const float*)d_in[7];
    const float* b2  = (const float*)d_in[8];
    const float* g2  = (const float*)d_in[9];
    const float* be2 = (const float*)d_in[10];
    const float* rm2 = (const float*)d_in[11];
    const float* rv2 = (const float*)d_in[12];
    const float* W3  = (const float*)d_in[13];
    const float* b3  = (const float*)d_in[14];
    const float* g3  = (const float*)d_in[15];
    const float* be3 = (const float*)d_in[16];
    const float* rm3 = (const float*)d_in[17];
    const float* rv3 = (const float*)d_in[18];
    const int* ei    = (const int*)d_in[19];
    const int* batch = (const int*)d_in[20];

    const int N = in_sizes[0] / 3;
    const int E = in_sizes[19] / 2;
    const int G = out_size / 32;
    const int* src = ei;
    const int* dst = ei + E;

    const int B = 256;
    const int nbins = (N + BINSIZE - 1) >> BINSHIFT;                  // 196 for N=100k
    const int cap = (((E / nbins) * 3) / 2 + 15) & ~15;               // 1.5x mean
    const int STAGE_BLOCKS = 512;
    const int chunk = (((E + STAGE_BLOCKS - 1) / STAGE_BLOCKS) + 3) & ~3;  // 4-aligned

    // workspace layout (staged aliases Tp, dead before layer1_gemm2 writes Tp)
    int*      gcur    = (int*)d_ws;                       // 256*GSTRIDE
    int*      cnt     = gcur + 256 * GSTRIDE;             // N
    float*    dinv    = (float*)(cnt + N);                // N
    int*      rowptr  = (int*)(dinv + N);                 // N
    int*      eidx    = rowptr + N;                       // E
    float4*   xs      = (float4*)(((uintptr_t)(eidx + E) + 15) & ~(uintptr_t)15);  // N
    uint32_t* Tp      = (uint32_t*)(xs + N);              // N*32 (layer-2 input, packed bf16)
    uint32_t* Tp2     = Tp + (size_t)N * 32;              // N*16 (layer-3 input, packed bf16)
    float*    gcnt    = (float*)(Tp2 + (size_t)N * 16);   // G
    uint32_t* staged  = Tp;                               // alias: dead before Tp written
    float*    out     = (float*)d_out;

    // ---- CSR build: multisplit stage -> per-bin fill ----
    hipMemsetAsync(gcur, 0, 256 * GSTRIDE * 4, stream);
    stage_ms_kernel<<<STAGE_BLOCKS, 256, 0, stream>>>(src, dst, gcur, staged, cap, nbins, E, chunk);
    fill_csr_kernel<<<nbins, 256, 0, stream>>>(staged, gcur, x, cap, nbins,
                                               rowptr, cnt, dinv, xs, eidx, N, out, gcnt, G);

    // ---- layer 1 + GEMM W2 fused: xs/CSR -> Tp (packed bf16) ----
    layer1_gemm2_kernel<<<(N + 31) / 32, 256, 0, stream>>>(
        xs, rowptr, cnt, eidx, dinv, W1, b1, g1, be1, rm1, rv1, W2, Tp, N);

    // ---- layer 2 gather + GEMM W3 fused: Tp/CSR -> Tp2 (packed bf16) ----
    layer2_gather_gemm3_kernel<<<(N + 31) / 32, 256, 0, stream>>>(
        Tp, rowptr, cnt, eidx, dinv, b2, g2, be2, rm2, rv2, W3, Tp2, N);

    // ---- layer 3 gather + mean-pool fused: Tp2/CSR -> out/gcnt atomics ----
    layer3_gather_pool_kernel<<<(N + 63) / 64, 256, 0, stream>>>(
        Tp2, rowptr, cnt, eidx, dinv, batch, b3, g3, be3, rm3, rv3, out, gcnt, N);

    pool_div_kernel<<<(G * 32 + B - 1) / B, B, 0, stream>>>(out, gcnt, G);
}

// Round 11
// 243.861 us; speedup vs baseline: 2.7634x; 1.0354x over previous
//
#include <hip/hip_runtime.h>

#define EPS_BN 1e-5f
#define NEG_SLOPE 0.01f

#define BINSHIFT 9                 // 512 nodes per bin (BINSHIFT 7 regressed: R3)
#define BINSIZE (1 << BINSHIFT)
#define NBINS_LDS 200              // supports N up to 102400
#define BUFCAP 24                  // LDS records per (block,bin)
#define GSTRIDE 16                 // gcur padding: one counter per 64B line

// ---- bf16x2 pack/unpack (RNE) ----
__device__ __forceinline__ uint32_t pack2_bf16(float x, float y) {
    uint32_t ux = __float_as_uint(x);
    uint32_t uy = __float_as_uint(y);
    ux = (ux + 0x7fffu + ((ux >> 16) & 1u)) >> 16;
    uy = (uy + 0x7fffu + ((uy >> 16) & 1u)) >> 16;
    return (uy << 16) | (ux & 0xffffu);
}
__device__ __forceinline__ float bf_lo(uint32_t p) { return __uint_as_float(p << 16); }
__device__ __forceinline__ float bf_hi(uint32_t p) { return __uint_as_float(p & 0xffff0000u); }

// quad-accumulate (same expression/order as R8 -> bit-identical results)
#define ACCQ(t0, t1, t2, t3)                                              \
    a0 += bf_lo(t0.x) + bf_lo(t2.x);  a1 += bf_hi(t0.x) + bf_hi(t2.x);    \
    a2 += bf_lo(t0.y) + bf_lo(t2.y);  a3 += bf_hi(t0.y) + bf_hi(t2.y);    \
    a4 += bf_lo(t0.z) + bf_lo(t2.z);  a5 += bf_hi(t0.z) + bf_hi(t2.z);    \
    a6 += bf_lo(t0.w) + bf_lo(t2.w);  a7 += bf_hi(t0.w) + bf_hi(t2.w);    \
    c0 += bf_lo(t1.x) + bf_lo(t3.x);  c1 += bf_hi(t1.x) + bf_hi(t3.x);    \
    c2 += bf_lo(t1.y) + bf_lo(t3.y);  c3 += bf_hi(t1.y) + bf_hi(t3.y);    \
    c4 += bf_lo(t1.z) + bf_lo(t3.z);  c5 += bf_hi(t1.z) + bf_hi(t3.z);    \
    c6 += bf_lo(t1.w) + bf_lo(t3.w);  c7 += bf_hi(t1.w) + bf_hi(t3.w)

// ---- phase A: LDS multisplit; 4 edges/thread/iter; packed 4-B records ----
__global__ void __launch_bounds__(256) stage_ms_kernel(
        const int* __restrict__ src, const int* __restrict__ dst,
        int* __restrict__ gcur, uint32_t* __restrict__ staged,
        int cap, int nbins, int E, int chunk) {
    __shared__ uint32_t bbuf[NBINS_LDS][BUFCAP];
    __shared__ int bcnt[NBINS_LDS];
    __shared__ int gpos[NBINS_LDS];
    for (int i = threadIdx.x; i < nbins; i += 256) bcnt[i] = 0;
    __syncthreads();
    int e0 = blockIdx.x * chunk;
    int e1 = min(e0 + chunk, E);
    for (int base = e0; base < e1; base += 1024) {       // 256 threads x 4 edges
        int e = base + threadIdx.x * 4;
        int s0, s1, s2, s3, d0, d1, d2, d3;
        int ne = 0;
        if (e + 4 <= e1) {
            int4 s4 = *(const int4*)(src + e);
            int4 d4 = *(const int4*)(dst + e);
            s0 = s4.x; s1 = s4.y; s2 = s4.z; s3 = s4.w;
            d0 = d4.x; d1 = d4.y; d2 = d4.z; d3 = d4.w;
            ne = 4;
        } else {
            int k = 0;
            for (; e + k < e1 && k < 4; ++k) {
                int sv = src[e + k], dv = dst[e + k];
                if (k == 0) { s0 = sv; d0 = dv; }
                else if (k == 1) { s1 = sv; d1 = dv; }
                else if (k == 2) { s2 = sv; d2 = dv; }
                else { s3 = sv; d3 = dv; }
            }
            ne = k;
        }
        #pragma unroll
        for (int k = 0; k < 4; ++k) {
            if (k >= ne) break;
            int s = (k == 0) ? s0 : (k == 1) ? s1 : (k == 2) ? s2 : s3;
            int d = (k == 0) ? d0 : (k == 1) ? d1 : (k == 2) ? d2 : d3;
            int bin = d >> BINSHIFT;
            uint32_t rec = ((uint32_t)s << BINSHIFT) | (uint32_t)(d & (BINSIZE - 1));
            int pos = atomicAdd(&bcnt[bin], 1);
            if (pos < BUFCAP) {
                bbuf[bin][pos] = rec;
            } else {                                     // rare: direct global append
                int gp = atomicAdd(&gcur[bin * GSTRIDE], 1);
                staged[(size_t)bin * cap + gp] = rec;
            }
        }
    }
    __syncthreads();
    // drain phase 1: one bin per THREAD -> all global atomics issue concurrently
    for (int b = threadIdx.x; b < nbins; b += 256) {
        int c = min(bcnt[b], BUFCAP);
        gpos[b] = (c > 0) ? atomicAdd(&gcur[b * GSTRIDE], c) : 0;
    }
    __syncthreads();
    // drain phase 2: cooperative 16-lane copy per bin
    int grp = threadIdx.x >> 4, lane = threadIdx.x & 15;
    for (int b = grp; b < nbins; b += 16) {
        int c = min(bcnt[b], BUFCAP);
        int gp = gpos[b];
        for (int i = lane; i < c; i += 16)
            staged[(size_t)b * cap + gp + i] = bbuf[b][i];
    }
}

// ---- phase B: per-bin CSR fill + rowptr/cnt/dinv/xs (packed recs) ----
__global__ void __launch_bounds__(256) fill_csr_kernel(
        const uint32_t* __restrict__ staged, const int* __restrict__ gcur,
        const float* __restrict__ x, int cap, int nbins,
        int* __restrict__ rowptr, int* __restrict__ cnt,
        float* __restrict__ dinv, float4* __restrict__ xs,
        int* __restrict__ eidx, int N,
        float* __restrict__ out, float* __restrict__ gcnt, int G) {
    __shared__ int lcnt[BINSIZE];
    __shared__ int loff[BINSIZE];
    __shared__ int ps[256];
    int bin = blockIdx.x;
    // ---- binbase = sum of gcur[i] for i < bin ----
    int v = (threadIdx.x < nbins && threadIdx.x < bin) ? gcur[threadIdx.x * GSTRIDE] : 0;
    ps[threadIdx.x] = v;
    __syncthreads();
    for (int off = 128; off; off >>= 1) {
        if (threadIdx.x < off) ps[threadIdx.x] += ps[threadIdx.x + off];
        __syncthreads();
    }
    int bb = ps[0];
    __syncthreads();
    // ---- block 0: zero pool accumulators ----
    if (bin == 0) {
        for (int i = threadIdx.x; i < G * 32; i += 256) out[i] = 0.f;
        for (int i = threadIdx.x; i < G; i += 256) gcnt[i] = 0.f;
    }
    int node0 = bin << BINSHIFT;
    int nn = min(BINSIZE, N - node0);
    int nrec = gcur[bin * GSTRIDE];
    const uint32_t* recs = staged + (size_t)bin * cap;
    for (int i = threadIdx.x; i < BINSIZE; i += 256) lcnt[i] = 0;
    __syncthreads();
    for (int t = threadIdx.x; t < nrec; t += 256)
        atomicAdd(&lcnt[recs[t] & (BINSIZE - 1)], 1);
    __syncthreads();
    int p0 = lcnt[2 * threadIdx.x], p1 = lcnt[2 * threadIdx.x + 1];
    int pv = p0 + p1;
    ps[threadIdx.x] = pv;
    __syncthreads();
    for (int off = 1; off < 256; off <<= 1) {
        int t = (threadIdx.x >= off) ? ps[threadIdx.x - off] : 0;
        __syncthreads();
        ps[threadIdx.x] += t;
        __syncthreads();
    }
    int base = ps[threadIdx.x] - pv;
    loff[2 * threadIdx.x] = base;
    loff[2 * threadIdx.x + 1] = base + p0;
    __syncthreads();
    for (int i = threadIdx.x; i < nn; i += 256) {
        int node = node0 + i;
        rowptr[node] = bb + loff[i];
        cnt[node] = lcnt[i];
        float di = rsqrtf((float)(lcnt[i] + 1));         // +1 self-loop
        dinv[node] = di;
        const float* xr = x + (size_t)node * 3;
        xs[node] = make_float4(xr[0] * di, xr[1] * di, xr[2] * di, 0.f);
        lcnt[i] = 0;                                     // reuse as cursor
    }
    __syncthreads();
    for (int t = threadIdx.x; t < nrec; t += 256) {
        uint32_t r = recs[t];
        int li = r & (BINSIZE - 1);
        int p = atomicAdd(&lcnt[li], 1);
        eidx[bb + loff[li] + p] = (int)(r >> BINSHIFT);  // block-private range
    }
}

// ---- fused layer1 + GEMM(64->64) + dinv-scale + bf16 pack (R8 body, LDS W2) ----
__global__ void __launch_bounds__(256) layer1_gemm2_kernel(
        const float4* __restrict__ xs, const int* __restrict__ rowptr,
        const int* __restrict__ cnt, const int* __restrict__ eidx,
        const float* __restrict__ dinv, const float* __restrict__ W1,
        const float* __restrict__ b1, const float* __restrict__ g1,
        const float* __restrict__ be1, const float* __restrict__ rm1,
        const float* __restrict__ rv1, const float* __restrict__ W2,
        uint32_t* __restrict__ Tp, int N) {
    __shared__ float sW1[3 * 64];
    __shared__ float sSc[64], sSh[64];
    __shared__ float sW2[64 * 64];
    __shared__ float sH[32][64];
    __shared__ float sDinv[32];
    for (int i = threadIdx.x; i < 64 * 64; i += 256) sW2[i] = W2[i];
    if (threadIdx.x < 192) sW1[threadIdx.x] = W1[threadIdx.x];
    if (threadIdx.x < 64) {
        int f = threadIdx.x;
        float sc = rsqrtf(rv1[f] + EPS_BN) * g1[f];
        sSc[f] = sc;
        sSh[f] = (b1[f] - rm1[f]) * sc + be1[f];
    }
    __syncthreads();
    int lane = threadIdx.x & 7;
    int nl = threadIdx.x >> 3;                           // 0..31
    int node = blockIdx.x * 32 + nl;
    int m = min(node, N - 1);                            // clamp; no early return (sync below)
    int start = rowptr[m], deg = cnt[m];
    float ax = 0.f, ay = 0.f, az = 0.f;
    for (int j = lane; j < deg; j += 8) {
        float4 v = xs[eidx[start + j]];
        ax += v.x; ay += v.y; az += v.z;
    }
    #pragma unroll
    for (int o = 4; o; o >>= 1) {
        ax += __shfl_xor(ax, o, 8);
        ay += __shfl_xor(ay, o, 8);
        az += __shfl_xor(az, o, 8);
    }
    float4 self = xs[m];
    float di = dinv[m];
    float gx = (ax + self.x) * di, gy = (ay + self.y) * di, gz = (az + self.z) * di;
    if (lane == 0) sDinv[nl] = di;
    int f0 = lane * 8;
    #pragma unroll
    for (int hh = 0; hh < 2; ++hh) {
        float4 hv;
        #pragma unroll
        for (int q = 0; q < 4; ++q) {
            int f = f0 + 4 * hh + q;
            float a = gx * sW1[f] + gy * sW1[64 + f] + gz * sW1[128 + f];
            float y = a * sSc[f] + sSh[f];
            ((float*)&hv)[q] = (y >= 0.f) ? y : NEG_SLOPE * y;
        }
        *(float4*)&sH[nl][f0 + 4 * hh] = hv;
    }
    __syncthreads();
    int fp = threadIdx.x & 31;                           // feature pair 0..31
    int ng = threadIdx.x >> 5;                           // 0..7
    const float2* w2 = (const float2*)sW2 + fp;          // float2 stride 32 per k
    const float4* sH0 = (const float4*)&sH[ng][0];
    const float4* sH1 = (const float4*)&sH[ng + 8][0];
    const float4* sH2 = (const float4*)&sH[ng + 16][0];
    const float4* sH3 = (const float4*)&sH[ng + 24][0];
    float a00 = 0.f, a01 = 0.f, a10 = 0.f, a11 = 0.f;
    float a20 = 0.f, a21 = 0.f, a30 = 0.f, a31 = 0.f;
    #pragma unroll 4
    for (int k4 = 0; k4 < 16; ++k4) {
        float4 h0 = sH0[k4];
        float4 h1 = sH1[k4];
        float4 h2 = sH2[k4];
        float4 h3 = sH3[k4];
        float2 w;
        w = w2[(4 * k4 + 0) * 32];
        a00 = fmaf(h0.x, w.x, a00); a01 = fmaf(h0.x, w.y, a01);
        a10 = fmaf(h1.x, w.x, a10); a11 = fmaf(h1.x, w.y, a11);
        a20 = fmaf(h2.x, w.x, a20); a21 = fmaf(h2.x, w.y, a21);
        a30 = fmaf(h3.x, w.x, a30); a31 = fmaf(h3.x, w.y, a31);
        w = w2[(4 * k4 + 1) * 32];
        a00 = fmaf(h0.y, w.x, a00); a01 = fmaf(h0.y, w.y, a01);
        a10 = fmaf(h1.y, w.x, a10); a11 = fmaf(h1.y, w.y, a11);
        a20 = fmaf(h2.y, w.x, a20); a21 = fmaf(h2.y, w.y, a21);
        a30 = fmaf(h3.y, w.x, a30); a31 = fmaf(h3.y, w.y, a31);
        w = w2[(4 * k4 + 2) * 32];
        a00 = fmaf(h0.z, w.x, a00); a01 = fmaf(h0.z, w.y, a01);
        a10 = fmaf(h1.z, w.x, a10); a11 = fmaf(h1.z, w.y, a11);
        a20 = fmaf(h2.z, w.x, a20); a21 = fmaf(h2.z, w.y, a21);
        a30 = fmaf(h3.z, w.x, a30); a31 = fmaf(h3.z, w.y, a31);
        w = w2[(4 * k4 + 3) * 32];
        a00 = fmaf(h0.w, w.x, a00); a01 = fmaf(h0.w, w.y, a01);
        a10 = fmaf(h1.w, w.x, a10); a11 = fmaf(h1.w, w.y, a11);
        a20 = fmaf(h2.w, w.x, a20); a21 = fmaf(h2.w, w.y, a21);
        a30 = fmaf(h3.w, w.x, a30); a31 = fmaf(h3.w, w.y, a31);
    }
    int base = blockIdx.x * 32;
    int n0 = base + ng, n1 = base + ng + 8, n2 = base + ng + 16, n3 = base + ng + 24;
    if (n0 < N) { float d = sDinv[ng];      Tp[(size_t)n0 * 32 + fp] = pack2_bf16(a00 * d, a01 * d); }
    if (n1 < N) { float d = sDinv[ng + 8];  Tp[(size_t)n1 * 32 + fp] = pack2_bf16(a10 * d, a11 * d); }
    if (n2 < N) { float d = sDinv[ng + 16]; Tp[(size_t)n2 * 32 + fp] = pack2_bf16(a20 * d, a21 * d); }
    if (n3 < N) { float d = sDinv[ng + 24]; Tp[(size_t)n3 * 32 + fp] = pack2_bf16(a30 * d, a31 * d); }
}

// ---- fused layer-2 gather + BN2 + LReLU + GEMM(64->32) + dinv-scale + pack.
// R11: 8-deep pipelined gather (8 uint4 LLC-misses in flight vs 4) -- R10's
// counters showed this kernel is LLC-latency bound (VALUBusy 23%, FETCH 5x Tp).
// Quad order + add expressions unchanged -> bit-identical.
__global__ void __launch_bounds__(256) layer2_gather_gemm3_kernel(
        const uint32_t* __restrict__ Tp, const int* __restrict__ rowptr,
        const int* __restrict__ cnt, const int* __restrict__ eidx,
        const float* __restrict__ dinv,
        const float* __restrict__ b2, const float* __restrict__ g2,
        const float* __restrict__ be2, const float* __restrict__ rm2,
        const float* __restrict__ rv2, const float* __restrict__ W3,
        uint32_t* __restrict__ Tp2, int N) {
    __shared__ float sW3[64 * 32];
    __shared__ float sSc[64], sSh[64];
    __shared__ float sH[32][64];
    __shared__ float sDinv[32];
    for (int i = threadIdx.x; i < 64 * 32; i += 256) sW3[i] = W3[i];
    if (threadIdx.x < 64) {
        int f = threadIdx.x;
        float sc = rsqrtf(rv2[f] + EPS_BN) * g2[f];
        sSc[f] = sc;
        sSh[f] = (b2[f] - rm2[f]) * sc + be2[f];
    }
    __syncthreads();
    int fq = threadIdx.x & 7;
    int nl = threadIdx.x >> 3;                           // 0..31
    int node = blockIdx.x * 32 + nl;
    int m = min(node, N - 1);
    const uint4* T4 = (const uint4*)Tp + fq;             // stride 8 uint4 per node
    int start = rowptr[m];
    int deg = cnt[m];
    uint4 ts = T4[(size_t)m * 8];
    float a0 = bf_lo(ts.x), a1 = bf_hi(ts.x), a2 = bf_lo(ts.y), a3 = bf_hi(ts.y);
    float a4 = bf_lo(ts.z), a5 = bf_hi(ts.z), a6 = bf_lo(ts.w), a7 = bf_hi(ts.w);
    float c0 = 0.f, c1 = 0.f, c2 = 0.f, c3 = 0.f;
    float c4 = 0.f, c5 = 0.f, c6 = 0.f, c7 = 0.f;
    const int* ep = eidx + start;
    int j = 0;
    int s0, s1, s2, s3, s4, s5, s6, s7;
    if (deg >= 8) {
        s0 = ep[0]; s1 = ep[1]; s2 = ep[2]; s3 = ep[3];
        s4 = ep[4]; s5 = ep[5]; s6 = ep[6]; s7 = ep[7];
        for (; j + 16 <= deg; j += 8) {                  // 8 in flight + idx prefetch
            uint4 t0 = T4[(size_t)s0 * 8];
            uint4 t1 = T4[(size_t)s1 * 8];
            uint4 t2 = T4[(size_t)s2 * 8];
            uint4 t3 = T4[(size_t)s3 * 8];
            uint4 t4 = T4[(size_t)s4 * 8];
            uint4 t5 = T4[(size_t)s5 * 8];
            uint4 t6 = T4[(size_t)s6 * 8];
            uint4 t7 = T4[(size_t)s7 * 8];
            s0 = ep[j + 8];  s1 = ep[j + 9];  s2 = ep[j + 10]; s3 = ep[j + 11];
            s4 = ep[j + 12]; s5 = ep[j + 13]; s6 = ep[j + 14]; s7 = ep[j + 15];
            ACCQ(t0, t1, t2, t3);
            ACCQ(t4, t5, t6, t7);
        }
        {                                                // final preloaded 8
            uint4 t0 = T4[(size_t)s0 * 8];
            uint4 t1 = T4[(size_t)s1 * 8];
            uint4 t2 = T4[(size_t)s2 * 8];
            uint4 t3 = T4[(size_t)s3 * 8];
            uint4 t4 = T4[(size_t)s4 * 8];
            uint4 t5 = T4[(size_t)s5 * 8];
            uint4 t6 = T4[(size_t)s6 * 8];
            uint4 t7 = T4[(size_t)s7 * 8];
            bool more = (j + 12 <= deg);
            if (more) { s0 = ep[j + 8]; s1 = ep[j + 9]; s2 = ep[j + 10]; s3 = ep[j + 11]; }
            ACCQ(t0, t1, t2, t3);
            ACCQ(t4, t5, t6, t7);
            j += 8;
            if (more) {
                uint4 u0 = T4[(size_t)s0 * 8];
                uint4 u1 = T4[(size_t)s1 * 8];
                uint4 u2 = T4[(size_t)s2 * 8];
                uint4 u3 = T4[(size_t)s3 * 8];
                ACCQ(u0, u1, u2, u3);
                j += 4;
            }
        }
    } else if (deg >= 4) {
        s0 = ep[0]; s1 = ep[1]; s2 = ep[2]; s3 = ep[3];
        uint4 t0 = T4[(size_t)s0 * 8];
        uint4 t1 = T4[(size_t)s1 * 8];
        uint4 t2 = T4[(size_t)s2 * 8];
        uint4 t3 = T4[(size_t)s3 * 8];
        ACCQ(t0, t1, t2, t3);
        j = 4;
    }
    for (; j < deg; ++j) {
        uint4 t0 = T4[(size_t)ep[j] * 8];
        a0 += bf_lo(t0.x); a1 += bf_hi(t0.x);
        a2 += bf_lo(t0.y); a3 += bf_hi(t0.y);
        a4 += bf_lo(t0.z); a5 += bf_hi(t0.z);
        a6 += bf_lo(t0.w); a7 += bf_hi(t0.w);
    }
    float di = dinv[m];
    if (fq == 0) sDinv[nl] = di;
    int f0 = 8 * fq;
    float av[8] = {a0 + c0, a1 + c1, a2 + c2, a3 + c3,
                   a4 + c4, a5 + c5, a6 + c6, a7 + c7};
    #pragma unroll
    for (int hh = 0; hh < 2; ++hh) {
        float4 hv;
        #pragma unroll
        for (int q = 0; q < 4; ++q) {
            int f = f0 + 4 * hh + q;
            float y = av[4 * hh + q] * di * sSc[f] + sSh[f];
            ((float*)&hv)[q] = (y >= 0.f) ? y : NEG_SLOPE * y;
        }
        *(float4*)&sH[nl][f0 + 4 * hh] = hv;
    }
    __syncthreads();
    int fp = threadIdx.x & 15;                           // feature pair 0..15
    int ng = threadIdx.x >> 4;                           // 0..15
    const float2* w3 = (const float2*)sW3 + fp;          // float2 stride 16 per k
    const float4* sHA = (const float4*)&sH[ng][0];
    const float4* sHB = (const float4*)&sH[ng + 16][0];
    float p0 = 0.f, p1 = 0.f, q0 = 0.f, q1 = 0.f;
    #pragma unroll 4
    for (int k4 = 0; k4 < 16; ++k4) {
        float4 hA = sHA[k4];
        float4 hB = sHB[k4];
        float2 w;
        w = w3[(4 * k4 + 0) * 16];
        p0 = fmaf(hA.x, w.x, p0); p1 = fmaf(hA.x, w.y, p1);
        q0 = fmaf(hB.x, w.x, q0); q1 = fmaf(hB.x, w.y, q1);
        w = w3[(4 * k4 + 1) * 16];
        p0 = fmaf(hA.y, w.x, p0); p1 = fmaf(hA.y, w.y, p1);
        q0 = fmaf(hB.y, w.x, q0); q1 = fmaf(hB.y, w.y, q1);
        w = w3[(4 * k4 + 2) * 16];
        p0 = fmaf(hA.z, w.x, p0); p1 = fmaf(hA.z, w.y, p1);
        q0 = fmaf(hB.z, w.x, q0); q1 = fmaf(hB.z, w.y, q1);
        w = w3[(4 * k4 + 3) * 16];
        p0 = fmaf(hA.w, w.x, p0); p1 = fmaf(hA.w, w.y, p1);
        q0 = fmaf(hB.w, w.x, q0); q1 = fmaf(hB.w, w.y, q1);
    }
    int base = blockIdx.x * 32;
    int nA = base + ng, nB = base + ng + 16;
    if (nA < N) { float d = sDinv[ng];      Tp2[(size_t)nA * 16 + fp] = pack2_bf16(p0 * d, p1 * d); }
    if (nB < N) { float d = sDinv[ng + 16]; Tp2[(size_t)nB * 16 + fp] = pack2_bf16(q0 * d, q1 * d); }
}

// ---- fused layer-3 gather + BN3 + LReLU + mean-pool accumulate.
// R11: same 8-deep pipelined gather as layer2.
#define SLOTS 16
__global__ void __launch_bounds__(256) layer3_gather_pool_kernel(
        const uint32_t* __restrict__ Tp2, const int* __restrict__ rowptr,
        const int* __restrict__ cnt, const int* __restrict__ eidx,
        const float* __restrict__ dinv, const int* __restrict__ batch,
        const float* __restrict__ b3, const float* __restrict__ g3,
        const float* __restrict__ be3, const float* __restrict__ rm3,
        const float* __restrict__ rv3,
        float* __restrict__ out, float* __restrict__ gcnt, int N) {
    __shared__ float sSc[32], sSh[32];
    __shared__ float sAcc[SLOTS][32];
    __shared__ int sCnt[SLOTS];
    if (threadIdx.x < 32) {
        int f = threadIdx.x;
        float sc = rsqrtf(rv3[f] + EPS_BN) * g3[f];
        sSc[f] = sc;
        sSh[f] = (b3[f] - rm3[f]) * sc + be3[f];
    }
    for (int i = threadIdx.x; i < SLOTS * 32; i += 256) ((float*)sAcc)[i] = 0.f;
    if (threadIdx.x < SLOTS) sCnt[threadIdx.x] = 0;
    __syncthreads();
    int fq = threadIdx.x & 3;
    int nl = threadIdx.x >> 2;                           // 0..63
    int node = blockIdx.x * 64 + nl;
    bool valid = node < N;
    int m = valid ? node : N - 1;
    const uint4* T4 = (const uint4*)Tp2 + fq;            // stride 4 uint4 per node
    int start = rowptr[m];
    int deg = cnt[m];
    uint4 ts = T4[(size_t)m * 4];
    float a0 = bf_lo(ts.x), a1 = bf_hi(ts.x), a2 = bf_lo(ts.y), a3 = bf_hi(ts.y);
    float a4 = bf_lo(ts.z), a5 = bf_hi(ts.z), a6 = bf_lo(ts.w), a7 = bf_hi(ts.w);
    float c0 = 0.f, c1 = 0.f, c2 = 0.f, c3 = 0.f;
    float c4 = 0.f, c5 = 0.f, c6 = 0.f, c7 = 0.f;
    const int* ep = eidx + start;
    int j = 0;
    int s0, s1, s2, s3, s4, s5, s6, s7;
    if (deg >= 8) {
        s0 = ep[0]; s1 = ep[1]; s2 = ep[2]; s3 = ep[3];
        s4 = ep[4]; s5 = ep[5]; s6 = ep[6]; s7 = ep[7];
        for (; j + 16 <= deg; j += 8) {                  // 8 in flight + idx prefetch
            uint4 t0 = T4[(size_t)s0 * 4];
            uint4 t1 = T4[(size_t)s1 * 4];
            uint4 t2 = T4[(size_t)s2 * 4];
            uint4 t3 = T4[(size_t)s3 * 4];
            uint4 t4 = T4[(size_t)s4 * 4];
            uint4 t5 = T4[(size_t)s5 * 4];
            uint4 t6 = T4[(size_t)s6 * 4];
            uint4 t7 = T4[(size_t)s7 * 4];
            s0 = ep[j + 8];  s1 = ep[j + 9];  s2 = ep[j + 10]; s3 = ep[j + 11];
            s4 = ep[j + 12]; s5 = ep[j + 13]; s6 = ep[j + 14]; s7 = ep[j + 15];
            ACCQ(t0, t1, t2, t3);
            ACCQ(t4, t5, t6, t7);
        }
        {                                                // final preloaded 8
            uint4 t0 = T4[(size_t)s0 * 4];
            uint4 t1 = T4[(size_t)s1 * 4];
            uint4 t2 = T4[(size_t)s2 * 4];
            uint4 t3 = T4[(size_t)s3 * 4];
            uint4 t4 = T4[(size_t)s4 * 4];
            uint4 t5 = T4[(size_t)s5 * 4];
            uint4 t6 = T4[(size_t)s6 * 4];
            uint4 t7 = T4[(size_t)s7 * 4];
            bool more = (j + 12 <= deg);
            if (more) { s0 = ep[j + 8]; s1 = ep[j + 9]; s2 = ep[j + 10]; s3 = ep[j + 11]; }
            ACCQ(t0, t1, t2, t3);
            ACCQ(t4, t5, t6, t7);
            j += 8;
            if (more) {
                uint4 u0 = T4[(size_t)s0 * 4];
                uint4 u1 = T4[(size_t)s1 * 4];
                uint4 u2 = T4[(size_t)s2 * 4];
                uint4 u3 = T4[(size_t)s3 * 4];
                ACCQ(u0, u1, u2, u3);
                j += 4;
            }
        }
    } else if (deg >= 4) {
        s0 = ep[0]; s1 = ep[1]; s2 = ep[2]; s3 = ep[3];
        uint4 t0 = T4[(size_t)s0 * 4];
        uint4 t1 = T4[(size_t)s1 * 4];
        uint4 t2 = T4[(size_t)s2 * 4];
        uint4 t3 = T4[(size_t)s3 * 4];
        ACCQ(t0, t1, t2, t3);
        j = 4;
    }
    for (; j < deg; ++j) {
        uint4 t0 = T4[(size_t)ep[j] * 4];
        a0 += bf_lo(t0.x); a1 += bf_hi(t0.x);
        a2 += bf_lo(t0.y); a3 += bf_hi(t0.y);
        a4 += bf_lo(t0.z); a5 += bf_hi(t0.z);
        a6 += bf_lo(t0.w); a7 += bf_hi(t0.w);
    }
    float di = dinv[m];
    int f0 = 8 * fq;
    float av[8] = {a0 + c0, a1 + c1, a2 + c2, a3 + c3,
                   a4 + c4, a5 + c5, a6 + c6, a7 + c7};
    float y[8];
    #pragma unroll
    for (int q = 0; q < 8; ++q) {
        float yy = av[q] * di * sSc[f0 + q] + sSh[f0 + q];
        y[q] = (yy >= 0.f) ? yy : NEG_SLOPE * yy;
    }
    int g0 = batch[blockIdx.x * 64];                     // first node of block, always < N
    if (valid) {
        int g = batch[node];
        int slot = g - g0;
        if (slot < SLOTS) {
            #pragma unroll
            for (int q = 0; q < 8; ++q) atomicAdd(&sAcc[slot][f0 + q], y[q]);
            if (fq == 0) atomicAdd(&sCnt[slot], 1);
        } else {                                         // rare: block spans many graphs
            #pragma unroll
            for (int q = 0; q < 8; ++q) atomicAdd(&out[(g << 5) + f0 + q], y[q]);
            if (fq == 0) atomicAdd(&gcnt[g], 1.f);
        }
    }
    __syncthreads();
    for (int i = threadIdx.x; i < SLOTS * 32; i += 256) {
        int s = i >> 5;
        if (sCnt[s] > 0)
            atomicAdd(&out[((g0 + s) << 5) + (i & 31)], ((float*)sAcc)[i]);
    }
    if (threadIdx.x < SLOTS && sCnt[threadIdx.x] > 0)
        atomicAdd(&gcnt[g0 + threadIdx.x], (float)sCnt[threadIdx.x]);
}

__global__ void pool_div_kernel(float* __restrict__ out, const float* __restrict__ gcnt, int G) {
    int tid = blockIdx.x * blockDim.x + threadIdx.x;
    if (tid < (G << 5)) out[tid] /= fmaxf(gcnt[tid >> 5], 1.0f);
}

extern "C" void kernel_launch(void* const* d_in, const int* in_sizes, int n_in,
                              void* d_out, int out_size, void* d_ws, size_t ws_size,
                              hipStream_t stream) {
    const float* x   = (const float*)d_in[0];
    const float* W1  = (const float*)d_in[1];
    const float* b1  = (const float*)d_in[2];
    const float* g1  = (const float*)d_in[3];
    const float* be1 = (const float*)d_in[4];
    const float* rm1 = (const float*)d_in[5];
    const float* rv1 = (const float*)d_in[6];
    const float* W2  = (const float*)d_in[7];
    const float* b2  = (const float*)d_in[8];
    const float* g2  = (const float*)d_in[9];
    const float* be2 = (const float*)d_in[10];
    const float* rm2 = (const float*)d_in[11];
    const float* rv2 = (const float*)d_in[12];
    const float* W3  = (const float*)d_in[13];
    const float* b3  = (const float*)d_in[14];
    const float* g3  = (const float*)d_in[15];
    const float* be3 = (const float*)d_in[16];
    const float* rm3 = (const float*)d_in[17];
    const float* rv3 = (const float*)d_in[18];
    const int* ei    = (const int*)d_in[19];
    const int* batch = (const int*)d_in[20];

    const int N = in_sizes[0] / 3;
    const int E = in_sizes[19] / 2;
    const int G = out_size / 32;
    const int* src = ei;
    const int* dst = ei + E;

    const int B = 256;
    const int nbins = (N + BINSIZE - 1) >> BINSHIFT;                  // 196 for N=100k
    const int cap = (((E / nbins) * 3) / 2 + 15) & ~15;               // 1.5x mean
    const int STAGE_BLOCKS = 512;
    const int chunk = (((E + STAGE_BLOCKS - 1) / STAGE_BLOCKS) + 3) & ~3;  // 4-aligned

    // workspace layout (staged aliases Tp, dead before layer1_gemm2 writes Tp)
    int*      gcur    = (int*)d_ws;                       // 256*GSTRIDE
    int*      cnt     = gcur + 256 * GSTRIDE;             // N
    float*    dinv    = (float*)(cnt + N);                // N
    int*      rowptr  = (int*)(dinv + N);                 // N
    int*      eidx    = rowptr + N;                       // E
    float4*   xs      = (float4*)(((uintptr_t)(eidx + E) + 15) & ~(uintptr_t)15);  // N
    uint32_t* Tp      = (uint32_t*)(xs + N);              // N*32 (layer-2 input, packed bf16)
    uint32_t* Tp2     = Tp + (size_t)N * 32;              // N*16 (layer-3 input, packed bf16)
    float*    gcnt    = (float*)(Tp2 + (size_t)N * 16);   // G
    uint32_t* staged  = Tp;                               // alias: dead before Tp written
    float*    out     = (float*)d_out;

    // ---- CSR build: multisplit stage -> per-bin fill ----
    hipMemsetAsync(gcur, 0, 256 * GSTRIDE * 4, stream);
    stage_ms_kernel<<<STAGE_BLOCKS, 256, 0, stream>>>(src, dst, gcur, staged, cap, nbins, E, chunk);
    fill_csr_kernel<<<nbins, 256, 0, stream>>>(staged, gcur, x, cap, nbins,
                                               rowptr, cnt, dinv, xs, eidx, N, out, gcnt, G);

    // ---- layer 1 + GEMM W2 fused: xs/CSR -> Tp (packed bf16) ----
    layer1_gemm2_kernel<<<(N + 31) / 32, 256, 0, stream>>>(
        xs, rowptr, cnt, eidx, dinv, W1, b1, g1, be1, rm1, rv1, W2, Tp, N);

    // ---- layer 2 gather + GEMM W3 fused: Tp/CSR -> Tp2 (packed bf16) ----
    layer2_gather_gemm3_kernel<<<(N + 31) / 32, 256, 0, stream>>>(
        Tp, rowptr, cnt, eidx, dinv, b2, g2, be2, rm2, rv2, W3, Tp2, N);

    // ---- layer 3 gather + mean-pool fused: Tp2/CSR -> out/gcnt atomics ----
    layer3_gather_pool_kernel<<<(N + 63) / 64, 256, 0, stream>>>(
        Tp2, rowptr, cnt, eidx, dinv, batch, b3, g3, be3, rm3, rv3, out, gcnt, N);

    pool_div_kernel<<<(G * 32 + B - 1) / B, B, 0, stream>>>(out, gcnt, G);
}

// Round 12
// 234.607 us; speedup vs baseline: 2.8724x; 1.0394x over previous
//
#include <hip/hip_runtime.h>

#define EPS_BN 1e-5f
#define NEG_SLOPE 0.01f

#define BINSHIFT 9                 // 512 nodes per bin (BINSHIFT 7 regressed: R3)
#define BINSIZE (1 << BINSHIFT)
#define NBINS_LDS 200              // supports N up to 102400
#define BUFCAP 24                  // LDS records per (block,bin)
#define GSTRIDE 16                 // gcur padding: one counter per 64B line

// ---- bf16x2 pack/unpack (RNE) ----
__device__ __forceinline__ uint32_t pack2_bf16(float x, float y) {
    uint32_t ux = __float_as_uint(x);
    uint32_t uy = __float_as_uint(y);
    ux = (ux + 0x7fffu + ((ux >> 16) & 1u)) >> 16;
    uy = (uy + 0x7fffu + ((uy >> 16) & 1u)) >> 16;
    return (uy << 16) | (ux & 0xffffu);
}
__device__ __forceinline__ float bf_lo(uint32_t p) { return __uint_as_float(p << 16); }
__device__ __forceinline__ float bf_hi(uint32_t p) { return __uint_as_float(p & 0xffff0000u); }

// ---- phase A: LDS multisplit; 4 edges/thread/iter; packed 4-B records ----
__global__ void __launch_bounds__(256) stage_ms_kernel(
        const int* __restrict__ src, const int* __restrict__ dst,
        int* __restrict__ gcur, uint32_t* __restrict__ staged,
        int cap, int nbins, int E, int chunk) {
    __shared__ uint32_t bbuf[NBINS_LDS][BUFCAP];
    __shared__ int bcnt[NBINS_LDS];
    __shared__ int gpos[NBINS_LDS];
    for (int i = threadIdx.x; i < nbins; i += 256) bcnt[i] = 0;
    __syncthreads();
    int e0 = blockIdx.x * chunk;
    int e1 = min(e0 + chunk, E);
    for (int base = e0; base < e1; base += 1024) {       // 256 threads x 4 edges
        int e = base + threadIdx.x * 4;
        int s0, s1, s2, s3, d0, d1, d2, d3;
        int ne = 0;
        if (e + 4 <= e1) {
            int4 s4 = *(const int4*)(src + e);
            int4 d4 = *(const int4*)(dst + e);
            s0 = s4.x; s1 = s4.y; s2 = s4.z; s3 = s4.w;
            d0 = d4.x; d1 = d4.y; d2 = d4.z; d3 = d4.w;
            ne = 4;
        } else {
            int k = 0;
            for (; e + k < e1 && k < 4; ++k) {
                int sv = src[e + k], dv = dst[e + k];
                if (k == 0) { s0 = sv; d0 = dv; }
                else if (k == 1) { s1 = sv; d1 = dv; }
                else if (k == 2) { s2 = sv; d2 = dv; }
                else { s3 = sv; d3 = dv; }
            }
            ne = k;
        }
        #pragma unroll
        for (int k = 0; k < 4; ++k) {
            if (k >= ne) break;
            int s = (k == 0) ? s0 : (k == 1) ? s1 : (k == 2) ? s2 : s3;
            int d = (k == 0) ? d0 : (k == 1) ? d1 : (k == 2) ? d2 : d3;
            int bin = d >> BINSHIFT;
            uint32_t rec = ((uint32_t)s << BINSHIFT) | (uint32_t)(d & (BINSIZE - 1));
            int pos = atomicAdd(&bcnt[bin], 1);
            if (pos < BUFCAP) {
                bbuf[bin][pos] = rec;
            } else {                                     // rare: direct global append
                int gp = atomicAdd(&gcur[bin * GSTRIDE], 1);
                staged[(size_t)bin * cap + gp] = rec;
            }
        }
    }
    __syncthreads();
    // drain phase 1: one bin per THREAD -> all global atomics issue concurrently
    for (int b = threadIdx.x; b < nbins; b += 256) {
        int c = min(bcnt[b], BUFCAP);
        gpos[b] = (c > 0) ? atomicAdd(&gcur[b * GSTRIDE], c) : 0;
    }
    __syncthreads();
    // drain phase 2: cooperative 16-lane copy per bin
    int grp = threadIdx.x >> 4, lane = threadIdx.x & 15;
    for (int b = grp; b < nbins; b += 16) {
        int c = min(bcnt[b], BUFCAP);
        int gp = gpos[b];
        for (int i = lane; i < c; i += 16)
            staged[(size_t)b * cap + gp + i] = bbuf[b][i];
    }
}

// ---- phase B: per-bin CSR fill + rowptr/cnt/dinv/xs (packed recs) ----
__global__ void __launch_bounds__(256) fill_csr_kernel(
        const uint32_t* __restrict__ staged, const int* __restrict__ gcur,
        const float* __restrict__ x, int cap, int nbins,
        int* __restrict__ rowptr, int* __restrict__ cnt,
        float* __restrict__ dinv, float4* __restrict__ xs,
        int* __restrict__ eidx, int N,
        float* __restrict__ out, float* __restrict__ gcnt, int G) {
    __shared__ int lcnt[BINSIZE];
    __shared__ int loff[BINSIZE];
    __shared__ int ps[256];
    int bin = blockIdx.x;
    // ---- binbase = sum of gcur[i] for i < bin ----
    int v = (threadIdx.x < nbins && threadIdx.x < bin) ? gcur[threadIdx.x * GSTRIDE] : 0;
    ps[threadIdx.x] = v;
    __syncthreads();
    for (int off = 128; off; off >>= 1) {
        if (threadIdx.x < off) ps[threadIdx.x] += ps[threadIdx.x + off];
        __syncthreads();
    }
    int bb = ps[0];
    __syncthreads();
    // ---- block 0: zero pool accumulators ----
    if (bin == 0) {
        for (int i = threadIdx.x; i < G * 32; i += 256) out[i] = 0.f;
        for (int i = threadIdx.x; i < G; i += 256) gcnt[i] = 0.f;
    }
    int node0 = bin << BINSHIFT;
    int nn = min(BINSIZE, N - node0);
    int nrec = gcur[bin * GSTRIDE];
    const uint32_t* recs = staged + (size_t)bin * cap;
    for (int i = threadIdx.x; i < BINSIZE; i += 256) lcnt[i] = 0;
    __syncthreads();
    for (int t = threadIdx.x; t < nrec; t += 256)
        atomicAdd(&lcnt[recs[t] & (BINSIZE - 1)], 1);
    __syncthreads();
    int p0 = lcnt[2 * threadIdx.x], p1 = lcnt[2 * threadIdx.x + 1];
    int pv = p0 + p1;
    ps[threadIdx.x] = pv;
    __syncthreads();
    for (int off = 1; off < 256; off <<= 1) {
        int t = (threadIdx.x >= off) ? ps[threadIdx.x - off] : 0;
        __syncthreads();
        ps[threadIdx.x] += t;
        __syncthreads();
    }
    int base = ps[threadIdx.x] - pv;
    loff[2 * threadIdx.x] = base;
    loff[2 * threadIdx.x + 1] = base + p0;
    __syncthreads();
    for (int i = threadIdx.x; i < nn; i += 256) {
        int node = node0 + i;
        rowptr[node] = bb + loff[i];
        cnt[node] = lcnt[i];
        float di = rsqrtf((float)(lcnt[i] + 1));         // +1 self-loop
        dinv[node] = di;
        const float* xr = x + (size_t)node * 3;
        xs[node] = make_float4(xr[0] * di, xr[1] * di, xr[2] * di, 0.f);
        lcnt[i] = 0;                                     // reuse as cursor
    }
    __syncthreads();
    for (int t = threadIdx.x; t < nrec; t += 256) {
        uint32_t r = recs[t];
        int li = r & (BINSIZE - 1);
        int p = atomicAdd(&lcnt[li], 1);
        eidx[bb + loff[li] + p] = (int)(r >> BINSHIFT);  // block-private range
    }
}

// ---- fused layer1 + GEMM(64->64) + dinv-scale + bf16 pack (R4/R8 body) ----
__global__ void __launch_bounds__(256) layer1_gemm2_kernel(
        const float4* __restrict__ xs, const int* __restrict__ rowptr,
        const int* __restrict__ cnt, const int* __restrict__ eidx,
        const float* __restrict__ dinv, const float* __restrict__ W1,
        const float* __restrict__ b1, const float* __restrict__ g1,
        const float* __restrict__ be1, const float* __restrict__ rm1,
        const float* __restrict__ rv1, const float* __restrict__ W2,
        uint32_t* __restrict__ Tp, int N) {
    __shared__ float sW1[3 * 64];
    __shared__ float sSc[64], sSh[64];
    __shared__ float sW2[64 * 64];
    __shared__ float sH[32][64];
    __shared__ float sDinv[32];
    for (int i = threadIdx.x; i < 64 * 64; i += 256) sW2[i] = W2[i];
    if (threadIdx.x < 192) sW1[threadIdx.x] = W1[threadIdx.x];
    if (threadIdx.x < 64) {
        int f = threadIdx.x;
        float sc = rsqrtf(rv1[f] + EPS_BN) * g1[f];
        sSc[f] = sc;
        sSh[f] = (b1[f] - rm1[f]) * sc + be1[f];
    }
    __syncthreads();
    int lane = threadIdx.x & 7;
    int nl = threadIdx.x >> 3;                           // 0..31
    int node = blockIdx.x * 32 + nl;
    int m = min(node, N - 1);                            // clamp; no early return (sync below)
    int start = rowptr[m], deg = cnt[m];
    float ax = 0.f, ay = 0.f, az = 0.f;
    for (int j = lane; j < deg; j += 8) {
        float4 v = xs[eidx[start + j]];
        ax += v.x; ay += v.y; az += v.z;
    }
    #pragma unroll
    for (int o = 4; o; o >>= 1) {
        ax += __shfl_xor(ax, o, 8);
        ay += __shfl_xor(ay, o, 8);
        az += __shfl_xor(az, o, 8);
    }
    float4 self = xs[m];
    float di = dinv[m];
    float gx = (ax + self.x) * di, gy = (ay + self.y) * di, gz = (az + self.z) * di;
    if (lane == 0) sDinv[nl] = di;
    int f0 = lane * 8;
    #pragma unroll
    for (int hh = 0; hh < 2; ++hh) {
        float4 hv;
        #pragma unroll
        for (int q = 0; q < 4; ++q) {
            int f = f0 + 4 * hh + q;
            float a = gx * sW1[f] + gy * sW1[64 + f] + gz * sW1[128 + f];
            float y = a * sSc[f] + sSh[f];
            ((float*)&hv)[q] = (y >= 0.f) ? y : NEG_SLOPE * y;
        }
        *(float4*)&sH[nl][f0 + 4 * hh] = hv;
    }
    __syncthreads();
    int fp = threadIdx.x & 31;                           // feature pair 0..31
    int ng = threadIdx.x >> 5;                           // 0..7
    const float2* w2 = (const float2*)sW2 + fp;          // float2 stride 32 per k
    const float4* sH0 = (const float4*)&sH[ng][0];
    const float4* sH1 = (const float4*)&sH[ng + 8][0];
    const float4* sH2 = (const float4*)&sH[ng + 16][0];
    const float4* sH3 = (const float4*)&sH[ng + 24][0];
    float a00 = 0.f, a01 = 0.f, a10 = 0.f, a11 = 0.f;
    float a20 = 0.f, a21 = 0.f, a30 = 0.f, a31 = 0.f;
    #pragma unroll 4
    for (int k4 = 0; k4 < 16; ++k4) {
        float4 h0 = sH0[k4];
        float4 h1 = sH1[k4];
        float4 h2 = sH2[k4];
        float4 h3 = sH3[k4];
        float2 w;
        w = w2[(4 * k4 + 0) * 32];
        a00 = fmaf(h0.x, w.x, a00); a01 = fmaf(h0.x, w.y, a01);
        a10 = fmaf(h1.x, w.x, a10); a11 = fmaf(h1.x, w.y, a11);
        a20 = fmaf(h2.x, w.x, a20); a21 = fmaf(h2.x, w.y, a21);
        a30 = fmaf(h3.x, w.x, a30); a31 = fmaf(h3.x, w.y, a31);
        w = w2[(4 * k4 + 1) * 32];
        a00 = fmaf(h0.y, w.x, a00); a01 = fmaf(h0.y, w.y, a01);
        a10 = fmaf(h1.y, w.x, a10); a11 = fmaf(h1.y, w.y, a11);
        a20 = fmaf(h2.y, w.x, a20); a21 = fmaf(h2.y, w.y, a21);
        a30 = fmaf(h3.y, w.x, a30); a31 = fmaf(h3.y, w.y, a31);
        w = w2[(4 * k4 + 2) * 32];
        a00 = fmaf(h0.z, w.x, a00); a01 = fmaf(h0.z, w.y, a01);
        a10 = fmaf(h1.z, w.x, a10); a11 = fmaf(h1.z, w.y, a11);
        a20 = fmaf(h2.z, w.x, a20); a21 = fmaf(h2.z, w.y, a21);
        a30 = fmaf(h3.z, w.x, a30); a31 = fmaf(h3.z, w.y, a31);
        w = w2[(4 * k4 + 3) * 32];
        a00 = fmaf(h0.w, w.x, a00); a01 = fmaf(h0.w, w.y, a01);
        a10 = fmaf(h1.w, w.x, a10); a11 = fmaf(h1.w, w.y, a11);
        a20 = fmaf(h2.w, w.x, a20); a21 = fmaf(h2.w, w.y, a21);
        a30 = fmaf(h3.w, w.x, a30); a31 = fmaf(h3.w, w.y, a31);
    }
    int base = blockIdx.x * 32;
    int n0 = base + ng, n1 = base + ng + 8, n2 = base + ng + 16, n3 = base + ng + 24;
    if (n0 < N) { float d = sDinv[ng];      Tp[(size_t)n0 * 32 + fp] = pack2_bf16(a00 * d, a01 * d); }
    if (n1 < N) { float d = sDinv[ng + 8];  Tp[(size_t)n1 * 32 + fp] = pack2_bf16(a10 * d, a11 * d); }
    if (n2 < N) { float d = sDinv[ng + 16]; Tp[(size_t)n2 * 32 + fp] = pack2_bf16(a20 * d, a21 * d); }
    if (n3 < N) { float d = sDinv[ng + 24]; Tp[(size_t)n3 * 32 + fp] = pack2_bf16(a30 * d, a31 * d); }
}

// ---- fused layer-2 gather + BN2 + LReLU + GEMM(64->32) + dinv-scale + pack.
// 4-deep pipelined gather (R8 best: 233.9us). R11's 8-deep variant regressed
// (243.9us: reg pressure + divergent drain at mean degree 12). Keep 4-deep.
__global__ void __launch_bounds__(256) layer2_gather_gemm3_kernel(
        const uint32_t* __restrict__ Tp, const int* __restrict__ rowptr,
        const int* __restrict__ cnt, const int* __restrict__ eidx,
        const float* __restrict__ dinv,
        const float* __restrict__ b2, const float* __restrict__ g2,
        const float* __restrict__ be2, const float* __restrict__ rm2,
        const float* __restrict__ rv2, const float* __restrict__ W3,
        uint32_t* __restrict__ Tp2, int N) {
    __shared__ float sW3[64 * 32];
    __shared__ float sSc[64], sSh[64];
    __shared__ float sH[32][64];
    __shared__ float sDinv[32];
    for (int i = threadIdx.x; i < 64 * 32; i += 256) sW3[i] = W3[i];
    if (threadIdx.x < 64) {
        int f = threadIdx.x;
        float sc = rsqrtf(rv2[f] + EPS_BN) * g2[f];
        sSc[f] = sc;
        sSh[f] = (b2[f] - rm2[f]) * sc + be2[f];
    }
    __syncthreads();
    int fq = threadIdx.x & 7;
    int nl = threadIdx.x >> 3;                           // 0..31
    int node = blockIdx.x * 32 + nl;
    int m = min(node, N - 1);
    const uint4* T4 = (const uint4*)Tp + fq;             // stride 8 uint4 per node
    int start = rowptr[m];
    int deg = cnt[m];
    uint4 ts = T4[(size_t)m * 8];
    float a0 = bf_lo(ts.x), a1 = bf_hi(ts.x), a2 = bf_lo(ts.y), a3 = bf_hi(ts.y);
    float a4 = bf_lo(ts.z), a5 = bf_hi(ts.z), a6 = bf_lo(ts.w), a7 = bf_hi(ts.w);
    float c0 = 0.f, c1 = 0.f, c2 = 0.f, c3 = 0.f;
    float c4 = 0.f, c5 = 0.f, c6 = 0.f, c7 = 0.f;
    const int* ep = eidx + start;
    int j = 0;
    int s0, s1, s2, s3;
    if (deg >= 4) { s0 = ep[0]; s1 = ep[1]; s2 = ep[2]; s3 = ep[3]; }
    for (; j + 8 <= deg; j += 4) {                       // pipelined: prefetch j+4..j+7
        uint4 t0 = T4[(size_t)s0 * 8];
        uint4 t1 = T4[(size_t)s1 * 8];
        uint4 t2 = T4[(size_t)s2 * 8];
        uint4 t3 = T4[(size_t)s3 * 8];
        s0 = ep[j + 4]; s1 = ep[j + 5]; s2 = ep[j + 6]; s3 = ep[j + 7];
        a0 += bf_lo(t0.x) + bf_lo(t2.x);  a1 += bf_hi(t0.x) + bf_hi(t2.x);
        a2 += bf_lo(t0.y) + bf_lo(t2.y);  a3 += bf_hi(t0.y) + bf_hi(t2.y);
        a4 += bf_lo(t0.z) + bf_lo(t2.z);  a5 += bf_hi(t0.z) + bf_hi(t2.z);
        a6 += bf_lo(t0.w) + bf_lo(t2.w);  a7 += bf_hi(t0.w) + bf_hi(t2.w);
        c0 += bf_lo(t1.x) + bf_lo(t3.x);  c1 += bf_hi(t1.x) + bf_hi(t3.x);
        c2 += bf_lo(t1.y) + bf_lo(t3.y);  c3 += bf_hi(t1.y) + bf_hi(t3.y);
        c4 += bf_lo(t1.z) + bf_lo(t3.z);  c5 += bf_hi(t1.z) + bf_hi(t3.z);
        c6 += bf_lo(t1.w) + bf_lo(t3.w);  c7 += bf_hi(t1.w) + bf_hi(t3.w);
    }
    if (j + 4 <= deg) {                                  // drain the prefetched quad
        uint4 t0 = T4[(size_t)s0 * 8];
        uint4 t1 = T4[(size_t)s1 * 8];
        uint4 t2 = T4[(size_t)s2 * 8];
        uint4 t3 = T4[(size_t)s3 * 8];
        a0 += bf_lo(t0.x) + bf_lo(t2.x);  a1 += bf_hi(t0.x) + bf_hi(t2.x);
        a2 += bf_lo(t0.y) + bf_lo(t2.y);  a3 += bf_hi(t0.y) + bf_hi(t2.y);
        a4 += bf_lo(t0.z) + bf_lo(t2.z);  a5 += bf_hi(t0.z) + bf_hi(t2.z);
        a6 += bf_lo(t0.w) + bf_lo(t2.w);  a7 += bf_hi(t0.w) + bf_hi(t2.w);
        c0 += bf_lo(t1.x) + bf_lo(t3.x);  c1 += bf_hi(t1.x) + bf_hi(t3.x);
        c2 += bf_lo(t1.y) + bf_lo(t3.y);  c3 += bf_hi(t1.y) + bf_hi(t3.y);
        c4 += bf_lo(t1.z) + bf_lo(t3.z);  c5 += bf_hi(t1.z) + bf_hi(t3.z);
        c6 += bf_lo(t1.w) + bf_lo(t3.w);  c7 += bf_hi(t1.w) + bf_hi(t3.w);
        j += 4;
    }
    for (; j < deg; ++j) {
        uint4 t0 = T4[(size_t)ep[j] * 8];
        a0 += bf_lo(t0.x); a1 += bf_hi(t0.x);
        a2 += bf_lo(t0.y); a3 += bf_hi(t0.y);
        a4 += bf_lo(t0.z); a5 += bf_hi(t0.z);
        a6 += bf_lo(t0.w); a7 += bf_hi(t0.w);
    }
    float di = dinv[m];
    if (fq == 0) sDinv[nl] = di;
    int f0 = 8 * fq;
    float av[8] = {a0 + c0, a1 + c1, a2 + c2, a3 + c3,
                   a4 + c4, a5 + c5, a6 + c6, a7 + c7};
    #pragma unroll
    for (int hh = 0; hh < 2; ++hh) {
        float4 hv;
        #pragma unroll
        for (int q = 0; q < 4; ++q) {
            int f = f0 + 4 * hh + q;
            float y = av[4 * hh + q] * di * sSc[f] + sSh[f];
            ((float*)&hv)[q] = (y >= 0.f) ? y : NEG_SLOPE * y;
        }
        *(float4*)&sH[nl][f0 + 4 * hh] = hv;
    }
    __syncthreads();
    int fp = threadIdx.x & 15;                           // feature pair 0..15
    int ng = threadIdx.x >> 4;                           // 0..15
    const float2* w3 = (const float2*)sW3 + fp;          // float2 stride 16 per k
    const float4* sHA = (const float4*)&sH[ng][0];
    const float4* sHB = (const float4*)&sH[ng + 16][0];
    float p0 = 0.f, p1 = 0.f, q0 = 0.f, q1 = 0.f;
    #pragma unroll 4
    for (int k4 = 0; k4 < 16; ++k4) {
        float4 hA = sHA[k4];
        float4 hB = sHB[k4];
        float2 w;
        w = w3[(4 * k4 + 0) * 16];
        p0 = fmaf(hA.x, w.x, p0); p1 = fmaf(hA.x, w.y, p1);
        q0 = fmaf(hB.x, w.x, q0); q1 = fmaf(hB.x, w.y, q1);
        w = w3[(4 * k4 + 1) * 16];
        p0 = fmaf(hA.y, w.x, p0); p1 = fmaf(hA.y, w.y, p1);
        q0 = fmaf(hB.y, w.x, q0); q1 = fmaf(hB.y, w.y, q1);
        w = w3[(4 * k4 + 2) * 16];
        p0 = fmaf(hA.z, w.x, p0); p1 = fmaf(hA.z, w.y, p1);
        q0 = fmaf(hB.z, w.x, q0); q1 = fmaf(hB.z, w.y, q1);
        w = w3[(4 * k4 + 3) * 16];
        p0 = fmaf(hA.w, w.x, p0); p1 = fmaf(hA.w, w.y, p1);
        q0 = fmaf(hB.w, w.x, q0); q1 = fmaf(hB.w, w.y, q1);
    }
    int base = blockIdx.x * 32;
    int nA = base + ng, nB = base + ng + 16;
    if (nA < N) { float d = sDinv[ng];      Tp2[(size_t)nA * 16 + fp] = pack2_bf16(p0 * d, p1 * d); }
    if (nB < N) { float d = sDinv[ng + 16]; Tp2[(size_t)nB * 16 + fp] = pack2_bf16(q0 * d, q1 * d); }
}

// ---- fused layer-3 gather + BN3 + LReLU + mean-pool accumulate (R8 body) ----
#define SLOTS 16
__global__ void __launch_bounds__(256) layer3_gather_pool_kernel(
        const uint32_t* __restrict__ Tp2, const int* __restrict__ rowptr,
        const int* __restrict__ cnt, const int* __restrict__ eidx,
        const float* __restrict__ dinv, const int* __restrict__ batch,
        const float* __restrict__ b3, const float* __restrict__ g3,
        const float* __restrict__ be3, const float* __restrict__ rm3,
        const float* __restrict__ rv3,
        float* __restrict__ out, float* __restrict__ gcnt, int N) {
    __shared__ float sSc[32], sSh[32];
    __shared__ float sAcc[SLOTS][32];
    __shared__ int sCnt[SLOTS];
    if (threadIdx.x < 32) {
        int f = threadIdx.x;
        float sc = rsqrtf(rv3[f] + EPS_BN) * g3[f];
        sSc[f] = sc;
        sSh[f] = (b3[f] - rm3[f]) * sc + be3[f];
    }
    for (int i = threadIdx.x; i < SLOTS * 32; i += 256) ((float*)sAcc)[i] = 0.f;
    if (threadIdx.x < SLOTS) sCnt[threadIdx.x] = 0;
    __syncthreads();
    int fq = threadIdx.x & 3;
    int nl = threadIdx.x >> 2;                           // 0..63
    int node = blockIdx.x * 64 + nl;
    bool valid = node < N;
    int m = valid ? node : N - 1;
    const uint4* T4 = (const uint4*)Tp2 + fq;            // stride 4 uint4 per node
    int start = rowptr[m];
    int deg = cnt[m];
    uint4 ts = T4[(size_t)m * 4];
    float a0 = bf_lo(ts.x), a1 = bf_hi(ts.x), a2 = bf_lo(ts.y), a3 = bf_hi(ts.y);
    float a4 = bf_lo(ts.z), a5 = bf_hi(ts.z), a6 = bf_lo(ts.w), a7 = bf_hi(ts.w);
    float c0 = 0.f, c1 = 0.f, c2 = 0.f, c3 = 0.f;
    float c4 = 0.f, c5 = 0.f, c6 = 0.f, c7 = 0.f;
    const int* ep = eidx + start;
    int j = 0;
    int s0, s1, s2, s3;
    if (deg >= 4) { s0 = ep[0]; s1 = ep[1]; s2 = ep[2]; s3 = ep[3]; }
    for (; j + 8 <= deg; j += 4) {                       // pipelined: prefetch j+4..j+7
        uint4 t0 = T4[(size_t)s0 * 4];
        uint4 t1 = T4[(size_t)s1 * 4];
        uint4 t2 = T4[(size_t)s2 * 4];
        uint4 t3 = T4[(size_t)s3 * 4];
        s0 = ep[j + 4]; s1 = ep[j + 5]; s2 = ep[j + 6]; s3 = ep[j + 7];
        a0 += bf_lo(t0.x) + bf_lo(t2.x);  a1 += bf_hi(t0.x) + bf_hi(t2.x);
        a2 += bf_lo(t0.y) + bf_lo(t2.y);  a3 += bf_hi(t0.y) + bf_hi(t2.y);
        a4 += bf_lo(t0.z) + bf_lo(t2.z);  a5 += bf_hi(t0.z) + bf_hi(t2.z);
        a6 += bf_lo(t0.w) + bf_lo(t2.w);  a7 += bf_hi(t0.w) + bf_hi(t2.w);
        c0 += bf_lo(t1.x) + bf_lo(t3.x);  c1 += bf_hi(t1.x) + bf_hi(t3.x);
        c2 += bf_lo(t1.y) + bf_lo(t3.y);  c3 += bf_hi(t1.y) + bf_hi(t3.y);
        c4 += bf_lo(t1.z) + bf_lo(t3.z);  c5 += bf_hi(t1.z) + bf_hi(t3.z);
        c6 += bf_lo(t1.w) + bf_lo(t3.w);  c7 += bf_hi(t1.w) + bf_hi(t3.w);
    }
    if (j + 4 <= deg) {                                  // drain the prefetched quad
        uint4 t0 = T4[(size_t)s0 * 4];
        uint4 t1 = T4[(size_t)s1 * 4];
        uint4 t2 = T4[(size_t)s2 * 4];
        uint4 t3 = T4[(size_t)s3 * 4];
        a0 += bf_lo(t0.x) + bf_lo(t2.x);  a1 += bf_hi(t0.x) + bf_hi(t2.x);
        a2 += bf_lo(t0.y) + bf_lo(t2.y);  a3 += bf_hi(t0.y) + bf_hi(t2.y);
        a4 += bf_lo(t0.z) + bf_lo(t2.z);  a5 += bf_hi(t0.z) + bf_hi(t2.z);
        a6 += bf_lo(t0.w) + bf_lo(t2.w);  a7 += bf_hi(t0.w) + bf_hi(t2.w);
        c0 += bf_lo(t1.x) + bf_lo(t3.x);  c1 += bf_hi(t1.x) + bf_hi(t3.x);
        c2 += bf_lo(t1.y) + bf_lo(t3.y);  c3 += bf_hi(t1.y) + bf_hi(t3.y);
        c4 += bf_lo(t1.z) + bf_lo(t3.z);  c5 += bf_hi(t1.z) + bf_hi(t3.z);
        c6 += bf_lo(t1.w) + bf_lo(t3.w);  c7 += bf_hi(t1.w) + bf_hi(t3.w);
        j += 4;
    }
    for (; j < deg; ++j) {
        uint4 t0 = T4[(size_t)ep[j] * 4];
        a0 += bf_lo(t0.x); a1 += bf_hi(t0.x);
        a2 += bf_lo(t0.y); a3 += bf_hi(t0.y);
        a4 += bf_lo(t0.z); a5 += bf_hi(t0.z);
        a6 += bf_lo(t0.w); a7 += bf_hi(t0.w);
    }
    float di = dinv[m];
    int f0 = 8 * fq;
    float av[8] = {a0 + c0, a1 + c1, a2 + c2, a3 + c3,
                   a4 + c4, a5 + c5, a6 + c6, a7 + c7};
    float y[8];
    #pragma unroll
    for (int q = 0; q < 8; ++q) {
        float yy = av[q] * di * sSc[f0 + q] + sSh[f0 + q];
        y[q] = (yy >= 0.f) ? yy : NEG_SLOPE * yy;
    }
    int g0 = batch[blockIdx.x * 64];                     // first node of block, always < N
    if (valid) {
        int g = batch[node];
        int slot = g - g0;
        if (slot < SLOTS) {
            #pragma unroll
            for (int q = 0; q < 8; ++q) atomicAdd(&sAcc[slot][f0 + q], y[q]);
            if (fq == 0) atomicAdd(&sCnt[slot], 1);
        } else {                                         // rare: block spans many graphs
            #pragma unroll
            for (int q = 0; q < 8; ++q) atomicAdd(&out[(g << 5) + f0 + q], y[q]);
            if (fq == 0) atomicAdd(&gcnt[g], 1.f);
        }
    }
    __syncthreads();
    for (int i = threadIdx.x; i < SLOTS * 32; i += 256) {
        int s = i >> 5;
        if (sCnt[s] > 0)
            atomicAdd(&out[((g0 + s) << 5) + (i & 31)], ((float*)sAcc)[i]);
    }
    if (threadIdx.x < SLOTS && sCnt[threadIdx.x] > 0)
        atomicAdd(&gcnt[g0 + threadIdx.x], (float)sCnt[threadIdx.x]);
}

__global__ void pool_div_kernel(float* __restrict__ out, const float* __restrict__ gcnt, int G) {
    int tid = blockIdx.x * blockDim.x + threadIdx.x;
    if (tid < (G << 5)) out[tid] /= fmaxf(gcnt[tid >> 5], 1.0f);
}

extern "C" void kernel_launch(void* const* d_in, const int* in_sizes, int n_in,
                              void* d_out, int out_size, void* d_ws, size_t ws_size,
                              hipStream_t stream) {
    const float* x   = (const float*)d_in[0];
    const float* W1  = (const float*)d_in[1];
    const float* b1  = (const float*)d_in[2];
    const float* g1  = (const float*)d_in[3];
    const float* be1 = (const float*)d_in[4];
    const float* rm1 = (const float*)d_in[5];
    const float* rv1 = (const float*)d_in[6];
    const float* W2  = (const float*)d_in[7];
    const float* b2  = (const float*)d_in[8];
    const float* g2  = (const float*)d_in[9];
    const float* be2 = (const float*)d_in[10];
    const float* rm2 = (const float*)d_in[11];
    const float* rv2 = (const float*)d_in[12];
    const float* W3  = (const float*)d_in[13];
    const float* b3  = (const float*)d_in[14];
    const float* g3  = (const float*)d_in[15];
    const float* be3 = (const float*)d_in[16];
    const float* rm3 = (const float*)d_in[17];
    const float* rv3 = (const float*)d_in[18];
    const int* ei    = (const int*)d_in[19];
    const int* batch = (const int*)d_in[20];

    const int N = in_sizes[0] / 3;
    const int E = in_sizes[19] / 2;
    const int G = out_size / 32;
    const int* src = ei;
    const int* dst = ei + E;

    const int B = 256;
    const int nbins = (N + BINSIZE - 1) >> BINSHIFT;                  // 196 for N=100k
    const int cap = (((E / nbins) * 3) / 2 + 15) & ~15;               // 1.5x mean
    const int STAGE_BLOCKS = 512;
    const int chunk = (((E + STAGE_BLOCKS - 1) / STAGE_BLOCKS) + 3) & ~3;  // 4-aligned

    // workspace layout (staged aliases Tp, dead before layer1_gemm2 writes Tp)
    int*      gcur    = (int*)d_ws;                       // 256*GSTRIDE
    int*      cnt     = gcur + 256 * GSTRIDE;             // N
    float*    dinv    = (float*)(cnt + N);                // N
    int*      rowptr  = (int*)(dinv + N);                 // N
    int*      eidx    = rowptr + N;                       // E
    float4*   xs      = (float4*)(((uintptr_t)(eidx + E) + 15) & ~(uintptr_t)15);  // N
    uint32_t* Tp      = (uint32_t*)(xs + N);              // N*32 (layer-2 input, packed bf16)
    uint32_t* Tp2     = Tp + (size_t)N * 32;              // N*16 (layer-3 input, packed bf16)
    float*    gcnt    = (float*)(Tp2 + (size_t)N * 16);   // G
    uint32_t* staged  = Tp;                               // alias: dead before Tp written
    float*    out     = (float*)d_out;

    // ---- CSR build: multisplit stage -> per-bin fill ----
    hipMemsetAsync(gcur, 0, 256 * GSTRIDE * 4, stream);
    stage_ms_kernel<<<STAGE_BLOCKS, 256, 0, stream>>>(src, dst, gcur, staged, cap, nbins, E, chunk);
    fill_csr_kernel<<<nbins, 256, 0, stream>>>(staged, gcur, x, cap, nbins,
                                               rowptr, cnt, dinv, xs, eidx, N, out, gcnt, G);

    // ---- layer 1 + GEMM W2 fused: xs/CSR -> Tp (packed bf16) ----
    layer1_gemm2_kernel<<<(N + 31) / 32, 256, 0, stream>>>(
        xs, rowptr, cnt, eidx, dinv, W1, b1, g1, be1, rm1, rv1, W2, Tp, N);

    // ---- layer 2 gather + GEMM W3 fused: Tp/CSR -> Tp2 (packed bf16) ----
    layer2_gather_gemm3_kernel<<<(N + 31) / 32, 256, 0, stream>>>(
        Tp, rowptr, cnt, eidx, dinv, b2, g2, be2, rm2, rv2, W3, Tp2, N);

    // ---- layer 3 gather + mean-pool fused: Tp2/CSR -> out/gcnt atomics ----
    layer3_gather_pool_kernel<<<(N + 63) / 64, 256, 0, stream>>>(
        Tp2, rowptr, cnt, eidx, dinv, batch, b3, g3, be3, rm3, rv3, out, gcnt, N);

    pool_div_kernel<<<(G * 32 + B - 1) / B, B, 0, stream>>>(out, gcnt, G);
}